// Round 3
// baseline (918.591 us; speedup 1.0000x reference)
//
#include <hip/hip_runtime.h>
#include <hip/hip_bf16.h>

#define N_B   16
#define CIO   512
#define LSEQ  384
#define DH    64
#define NH    8
#define CHID  512
#define ME    384
#define DG    8

typedef __hip_bfloat16 bf16;

__device__ __forceinline__ float b2f(bf16 v) { return __bfloat162float(v); }

// ---------------------------------------------------------------------------
// GEMM: y[n,o,l] = sum_c W[o,c] * X[n,c,l]   (+bias for MODE 2)
// MODE 0: X = x + xorg*qkorg_res[c/8] + abspos*qkpos_res[c/8]   (qk path)
// MODE 1: X = x + xorg*vorg_res[c/8]                            (v path)
// MODE 2: X = ctx (bf16 ws), adds dense bias, writes f32 out
// 64x64 tile, 256 threads, 4x4 accum per thread, K-tile 16.
// ---------------------------------------------------------------------------
template<int MODE>
__launch_bounds__(256)
__global__ void gemm_kernel(const float* __restrict__ W,
                            const float* __restrict__ x,
                            const float* __restrict__ xorg,
                            const float* __restrict__ abspos,
                            const float* __restrict__ res1,
                            const float* __restrict__ res2,
                            const bf16* __restrict__ xin,
                            const float* __restrict__ bias,
                            bf16* __restrict__ outb,
                            float* __restrict__ outf)
{
    __shared__ float Ws[64][17];       // [o][k], padded
    __shared__ float Xs[16][64];       // [k][l]
    __shared__ float r1[CIO / DG];
    __shared__ float r2[CIO / DG];

    const int tid = threadIdx.x;
    const int l0 = blockIdx.x * 64;
    const int o0 = blockIdx.y * 64;
    const int n  = blockIdx.z;

    if (MODE != 2) {
        if (tid < CIO / DG) {
            r1[tid] = res1[tid];
            r2[tid] = (MODE == 0) ? res2[tid] : 0.f;
        }
    }
    __syncthreads();

    const int tx = tid & 15;    // l group
    const int ty = tid >> 4;    // o group

    float acc[4][4];
    #pragma unroll
    for (int i = 0; i < 4; i++)
        #pragma unroll
        for (int j = 0; j < 4; j++) acc[i][j] = 0.f;

    const int wc = tid & 15;    // c within W tile
    const int wo = tid >> 4;    // o base within W tile
    const int xl = tid & 63;    // l within X tile
    const int xc = tid >> 6;    // c base within X tile

    for (int k0 = 0; k0 < CIO; k0 += 16) {
        #pragma unroll
        for (int r = 0; r < 4; r++) {
            int o = wo + r * 16;
            Ws[o][wc] = W[(size_t)(o0 + o) * CIO + k0 + wc];
        }
        #pragma unroll
        for (int r = 0; r < 4; r++) {
            int c = k0 + xc + r * 4;
            size_t gi = ((size_t)n * CIO + c) * LSEQ + l0 + xl;
            float xv;
            if (MODE == 2) {
                xv = b2f(xin[gi]);
            } else {
                xv = x[gi] + r1[c >> 3] * xorg[gi];
                if (MODE == 0) xv += r2[c >> 3] * abspos[gi];
            }
            Xs[xc + r * 4][xl] = xv;
        }
        __syncthreads();
        #pragma unroll
        for (int kk = 0; kk < 16; kk++) {
            float a[4], b[4];
            #pragma unroll
            for (int i = 0; i < 4; i++) a[i] = Ws[ty * 4 + i][kk];
            #pragma unroll
            for (int j = 0; j < 4; j++) b[j] = Xs[kk][tx * 4 + j];
            #pragma unroll
            for (int i = 0; i < 4; i++)
                #pragma unroll
                for (int j = 0; j < 4; j++) acc[i][j] += a[i] * b[j];
        }
        __syncthreads();
    }

    #pragma unroll
    for (int i = 0; i < 4; i++) {
        int o = o0 + ty * 4 + i;
        float bv = (MODE == 2) ? bias[o] : 0.f;
        #pragma unroll
        for (int j = 0; j < 4; j++) {
            int l = l0 + tx * 4 + j;
            size_t oi = ((size_t)n * CHID + o) * LSEQ + l;
            if (MODE == 2) outf[oi] = acc[i][j] + bv;
            else           outb[oi] = __float2bfloat16(acc[i][j]);
        }
    }
}

// ---------------------------------------------------------------------------
// gate[n,h,l] = sum_c gate_w[h,c] * x[n,c,l] + gate_b[h]     (raw x!)
// ---------------------------------------------------------------------------
__launch_bounds__(384)
__global__ void gate_kernel(const float* __restrict__ x,
                            const float* __restrict__ gw,
                            const float* __restrict__ gb,
                            float* __restrict__ gate)
{
    __shared__ float w[CIO];
    const int h = blockIdx.x, n = blockIdx.y;
    const int tid = threadIdx.x;   // = l
    for (int c = tid; c < CIO; c += 384) w[c] = gw[h * CIO + c];
    __syncthreads();
    float s = gb[h];
    const float* xp = x + (size_t)n * CIO * LSEQ + tid;
    #pragma unroll 4
    for (int c = 0; c < CIO; c++) s += w[c] * xp[(size_t)c * LSEQ];
    gate[((size_t)n * NH + h) * LSEQ + tid] = s;
}

// ---------------------------------------------------------------------------
// Attention per (n, h, query-chunk of 96). Block = 384 threads.
// K (64x384) staged in LDS as bf16. Per query: 384-thread score row,
// block softmax, PV with bf16x8 vector V loads, reduce 6 partials per d.
// ---------------------------------------------------------------------------
__launch_bounds__(384)
__global__ void attn_kernel(const bf16* __restrict__ q,
                            const bf16* __restrict__ k,
                            const bf16* __restrict__ v,
                            const float* __restrict__ gate,
                            const float* __restrict__ mask,
                            const float* __restrict__ norm,
                            const float* __restrict__ relpos,
                            bf16* __restrict__ ctx)
{
    __shared__ bf16  kl[DH * LSEQ];       // 48 KB
    __shared__ float qcol[DH];
    __shared__ float pl[LSEQ];
    __shared__ float radd[LSEQ];
    __shared__ float relp[2 * ME - 1];
    __shared__ float part[LSEQ];
    __shared__ float red[8];

    const int tid = threadIdx.x;
    const int qc = blockIdx.x, h = blockIdx.y, n = blockIdx.z;
    const size_t hb = ((size_t)n * CHID + h * DH) * LSEQ;

    // stage K (16B vector copies; all bases 16B-aligned)
    {
        const uint4* kg = (const uint4*)(k + hb);
        uint4* kld = (uint4*)kl;
        for (int i = tid; i < DH * LSEQ / 8; i += 384) kld[i] = kg[i];
    }
    radd[tid] = gate[((size_t)n * NH + h) * LSEQ + tid]
              + mask[(size_t)n * LSEQ + tid];
    for (int i = tid; i < 2 * ME - 1; i += 384) relp[i] = relpos[i];
    const float inv_norm = 1.0f / norm[n];
    __syncthreads();

    const int lane = tid & 63;
    const int wid  = tid >> 6;

    for (int ii = 0; ii < 96; ii++) {
        const int i = qc * 96 + ii;
        if (tid < DH) qcol[tid] = b2f(q[hb + (size_t)tid * LSEQ + i]);
        __syncthreads();

        // scores: s_j = q . k_j  (+relpos +gate +mask) / norm
        float s;
        {
            const int j = tid;
            float acc = 0.f;
            #pragma unroll 8
            for (int d = 0; d < DH; d++) acc += qcol[d] * b2f(kl[d * LSEQ + j]);
            int idx = ME - i + j;
            if (idx > 2 * ME - 2) idx = 2 * ME - 2;
            s = (acc + relp[idx] + radd[j]) * inv_norm;
        }

        // block softmax over 384 values
        float m = s;
        #pragma unroll
        for (int off = 32; off > 0; off >>= 1) m = fmaxf(m, __shfl_down(m, off));
        if (lane == 0) red[wid] = m;
        __syncthreads();
        if (tid == 0) {
            float mm = red[0];
            for (int w = 1; w < 6; w++) mm = fmaxf(mm, red[w]);
            red[6] = mm;
        }
        __syncthreads();
        m = red[6];
        float e = __expf(s - m);
        float sum = e;
        #pragma unroll
        for (int off = 32; off > 0; off >>= 1) sum += __shfl_down(sum, off);
        if (lane == 0) red[wid] = sum;
        __syncthreads();
        if (tid == 0) {
            float ss = red[0];
            for (int w = 1; w < 6; w++) ss += red[w];
            red[6] = 1.0f / ss;
        }
        __syncthreads();
        pl[tid] = e * red[6];
        __syncthreads();

        // PV: out[d,i] = sum_j p_j v[d,j];  tid = d*6 + c, c covers 64 j's
        {
            const int d = tid / 6, c = tid % 6;
            const int j0 = c * 64;
            const uint4* vp4 = (const uint4*)(v + hb + (size_t)d * LSEQ + j0);
            float acc = 0.f;
            #pragma unroll
            for (int t = 0; t < 8; t++) {
                uint4 pk4 = vp4[t];
                const bf16* vv = (const bf16*)&pk4;
                #pragma unroll
                for (int u = 0; u < 8; u++)
                    acc += pl[j0 + t * 8 + u] * b2f(vv[u]);
            }
            part[tid] = acc;
        }
        __syncthreads();
        if (tid < DH) {
            float o = 0.f;
            #pragma unroll
            for (int c = 0; c < 6; c++) o += part[tid * 6 + c];
            ctx[hb + (size_t)tid * LSEQ + i] = __float2bfloat16(o);
        }
        __syncthreads();
    }
}

// ---------------------------------------------------------------------------
extern "C" void kernel_launch(void* const* d_in, const int* in_sizes, int n_in,
                              void* d_out, int out_size, void* d_ws, size_t ws_size,
                              hipStream_t stream)
{
    const float* x       = (const float*)d_in[0];
    const float* xorg    = (const float*)d_in[1];
    const float* abspos  = (const float*)d_in[2];
    const float* mask    = (const float*)d_in[3];
    const float* norm    = (const float*)d_in[4];
    const float* qkpos   = (const float*)d_in[5];
    const float* qkorg   = (const float*)d_in[6];
    const float* vorg    = (const float*)d_in[7];
    const float* relpos  = (const float*)d_in[8];
    const float* gate_w  = (const float*)d_in[9];
    const float* gate_b  = (const float*)d_in[10];
    const float* q_w     = (const float*)d_in[11];
    const float* k_w     = (const float*)d_in[12];
    const float* v_w     = (const float*)d_in[13];
    const float* dense_w = (const float*)d_in[14];
    const float* dense_b = (const float*)d_in[15];
    float* out = (float*)d_out;

    const size_t TEN = (size_t)N_B * CHID * LSEQ * sizeof(bf16);  // 6291456 B
    char* ws = (char*)d_ws;
    bf16*  qb   = (bf16*)(ws);
    bf16*  kb   = (bf16*)(ws + TEN);
    bf16*  vb   = (bf16*)(ws + 2 * TEN);
    bf16*  ctx  = (bf16*)(ws + 3 * TEN);
    float* gate = (float*)(ws + 4 * TEN);

    dim3 gg(LSEQ / 64, CHID / 64, N_B);
    gemm_kernel<0><<<gg, 256, 0, stream>>>(q_w, x, xorg, abspos, qkorg, qkpos,
                                           nullptr, nullptr, qb, nullptr);
    gemm_kernel<0><<<gg, 256, 0, stream>>>(k_w, x, xorg, abspos, qkorg, qkpos,
                                           nullptr, nullptr, kb, nullptr);
    gemm_kernel<1><<<gg, 256, 0, stream>>>(v_w, x, xorg, abspos, vorg, nullptr,
                                           nullptr, nullptr, vb, nullptr);
    gate_kernel<<<dim3(NH, N_B), 384, 0, stream>>>(x, gate_w, gate_b, gate);
    attn_kernel<<<dim3(4, NH, N_B), 384, 0, stream>>>(qb, kb, vb, gate, mask,
                                                      norm, relpos, ctx);
    gemm_kernel<2><<<gg, 256, 0, stream>>>(dense_w, nullptr, nullptr, nullptr,
                                           nullptr, nullptr, ctx, dense_b, nullptr, out);
}

// Round 4
// 421.789 us; speedup vs baseline: 2.1778x; 2.1778x over previous
//
#include <hip/hip_runtime.h>
#include <hip/hip_bf16.h>

#define N_B   16
#define CIO   512
#define LSEQ  384
#define DH    64
#define NH    8
#define CHID  512
#define ME    384
#define DG    8

typedef __hip_bfloat16 bf16;
typedef __attribute__((ext_vector_type(8))) short bf16x8;
typedef __attribute__((ext_vector_type(4))) float f32x4;

__device__ __forceinline__ float b2f(bf16 v) { return __bfloat162float(v); }
__device__ __forceinline__ unsigned short f2bs(float f) {
    bf16 h = __float2bfloat16(f);
    union { bf16 b; unsigned short u; } cv; cv.b = h; return cv.u;
}

// ---------------------------------------------------------------------------
// GEMM: y[n,o,l] = sum_c W[o,c] * X[n,c,l]   (+bias for MODE 2)
// MODE 0: X = x + xorg*qkorg_res[c/8] + abspos*qkpos_res[c/8]   (qk path)
// MODE 1: X = x + xorg*vorg_res[c/8]                            (v path)
// MODE 2: X = ctx (bf16 ws), adds dense bias, writes f32 out
// TRANS=1: write output transposed as outb[n][h=o>>6][l][d=o&63] (for MFMA attn)
// ---------------------------------------------------------------------------
template<int MODE, int TRANS>
__launch_bounds__(256)
__global__ void gemm_kernel(const float* __restrict__ W,
                            const float* __restrict__ x,
                            const float* __restrict__ xorg,
                            const float* __restrict__ abspos,
                            const float* __restrict__ res1,
                            const float* __restrict__ res2,
                            const bf16* __restrict__ xin,
                            const float* __restrict__ bias,
                            bf16* __restrict__ outb,
                            float* __restrict__ outf)
{
    __shared__ float Ws[64][17];       // [o][k], padded
    __shared__ float Xs[16][64];       // [k][l]
    __shared__ float r1[CIO / DG];
    __shared__ float r2[CIO / DG];

    const int tid = threadIdx.x;
    const int l0 = blockIdx.x * 64;
    const int o0 = blockIdx.y * 64;
    const int n  = blockIdx.z;

    if (MODE != 2) {
        if (tid < CIO / DG) {
            r1[tid] = res1[tid];
            r2[tid] = (MODE == 0) ? res2[tid] : 0.f;
        }
    }
    __syncthreads();

    const int tx = tid & 15;    // l group
    const int ty = tid >> 4;    // o group

    float acc[4][4];
    #pragma unroll
    for (int i = 0; i < 4; i++)
        #pragma unroll
        for (int j = 0; j < 4; j++) acc[i][j] = 0.f;

    const int wc = tid & 15;    // c within W tile
    const int wo = tid >> 4;    // o base within W tile
    const int xl = tid & 63;    // l within X tile
    const int xc = tid >> 6;    // c base within X tile

    for (int k0 = 0; k0 < CIO; k0 += 16) {
        #pragma unroll
        for (int r = 0; r < 4; r++) {
            int o = wo + r * 16;
            Ws[o][wc] = W[(size_t)(o0 + o) * CIO + k0 + wc];
        }
        #pragma unroll
        for (int r = 0; r < 4; r++) {
            int c = k0 + xc + r * 4;
            size_t gi = ((size_t)n * CIO + c) * LSEQ + l0 + xl;
            float xv;
            if (MODE == 2) {
                xv = b2f(xin[gi]);
            } else {
                xv = x[gi] + r1[c >> 3] * xorg[gi];
                if (MODE == 0) xv += r2[c >> 3] * abspos[gi];
            }
            Xs[xc + r * 4][xl] = xv;
        }
        __syncthreads();
        #pragma unroll
        for (int kk = 0; kk < 16; kk++) {
            float a[4], b[4];
            #pragma unroll
            for (int i = 0; i < 4; i++) a[i] = Ws[ty * 4 + i][kk];
            #pragma unroll
            for (int j = 0; j < 4; j++) b[j] = Xs[kk][tx * 4 + j];
            #pragma unroll
            for (int i = 0; i < 4; i++)
                #pragma unroll
                for (int j = 0; j < 4; j++) acc[i][j] += a[i] * b[j];
        }
        __syncthreads();
    }

    if (TRANS) {
        // outb[((n*NH + h)*LSEQ + l)*DH + d], h = o0>>6, d = ty*4 + i
        #pragma unroll
        for (int j = 0; j < 4; j++) {
            int l = l0 + tx * 4 + j;
            ushort4 pk;
            pk.x = f2bs(acc[0][j]); pk.y = f2bs(acc[1][j]);
            pk.z = f2bs(acc[2][j]); pk.w = f2bs(acc[3][j]);
            *(ushort4*)&outb[(((size_t)n * NH + (o0 >> 6)) * LSEQ + l) * DH + ty * 4] = pk;
        }
    } else {
        #pragma unroll
        for (int i = 0; i < 4; i++) {
            int o = o0 + ty * 4 + i;
            float bv = (MODE == 2) ? bias[o] : 0.f;
            #pragma unroll
            for (int j = 0; j < 4; j++) {
                int l = l0 + tx * 4 + j;
                size_t oi = ((size_t)n * CHID + o) * LSEQ + l;
                if (MODE == 2) outf[oi] = acc[i][j] + bv;
                else           outb[oi] = __float2bfloat16(acc[i][j]);
            }
        }
    }
}

// ---------------------------------------------------------------------------
// gate[n,h,l] = sum_c gate_w[h,c] * x[n,c,l] + gate_b[h]     (raw x!)
// ---------------------------------------------------------------------------
__launch_bounds__(384)
__global__ void gate_kernel(const float* __restrict__ x,
                            const float* __restrict__ gw,
                            const float* __restrict__ gb,
                            float* __restrict__ gate)
{
    __shared__ float w[CIO];
    const int h = blockIdx.x, n = blockIdx.y;
    const int tid = threadIdx.x;   // = l
    for (int c = tid; c < CIO; c += 384) w[c] = gw[h * CIO + c];
    __syncthreads();
    float s = gb[h];
    const float* xp = x + (size_t)n * CIO * LSEQ + tid;
    #pragma unroll 4
    for (int c = 0; c < CIO; c++) s += w[c] * xp[(size_t)c * LSEQ];
    gate[((size_t)n * NH + h) * LSEQ + tid] = s;
}

// ---------------------------------------------------------------------------
// MFMA attention: block = (n, h, 64-query tile), 256 thr = 4 waves.
// Wave w owns query rows m0=16w..16w+15 of the tile.
// Phase1: S = Q^T K via mfma 16x16x32 (A-frags from qt global, B from Kt LDS)
// softmax in C-layout regs (row = 4*(lane>>4)+reg, col = lane&15)
// Phase2: O = P V^T, P via LDS (aliases Kt), V^T B-frags direct from global.
// ---------------------------------------------------------------------------
__launch_bounds__(256)
__global__ void attn2_kernel(const bf16* __restrict__ qt,   // [n][h][i][d]
                             const bf16* __restrict__ kt,   // [n][h][j][d]
                             const bf16* __restrict__ v,    // [n][h*64+d][j]
                             const float* __restrict__ gate,
                             const float* __restrict__ mask,
                             const float* __restrict__ norm,
                             const float* __restrict__ relpos,
                             bf16* __restrict__ ctx)
{
    __shared__ __align__(16) char smem[55296];   // Kt[384][72] | P[64][400] | O[64][72]
    __shared__ float relp_s[2 * ME - 1];
    __shared__ float radd_s[LSEQ];

    bf16* Kt = (bf16*)smem;
    bf16* P  = (bf16*)smem;
    bf16* O  = (bf16*)smem;

    const int tid = threadIdx.x;
    const int i0 = blockIdx.x * 64;
    const int h = blockIdx.y, n = blockIdx.z;
    const int lane = tid & 63;
    const int w = tid >> 6;
    const int l15 = lane & 15, g = lane >> 4;
    const int m0 = w * 16;

    const size_t nh = (size_t)n * NH + h;
    const bf16* kt_g = kt + nh * LSEQ * DH;
    const bf16* vg   = v + ((size_t)n * CHID + h * DH) * LSEQ;

    // ---- stage K (contiguous copy, rows padded 64->72) + radd + relp ----
    #pragma unroll
    for (int t = 0; t < 12; t++) {
        int idx = t * 256 + tid;
        int j = idx >> 3, u = idx & 7;
        *(uint4*)&Kt[j * 72 + u * 8] = *(const uint4*)&kt_g[j * 64 + u * 8];
    }
    for (int i = tid; i < LSEQ; i += 256)
        radd_s[i] = gate[nh * LSEQ + i] + mask[(size_t)n * LSEQ + i];
    for (int i = tid; i < 2 * ME - 1; i += 256) relp_s[i] = relpos[i];

    // ---- Q A-frags: lane holds Q^T[m = m0+l15][k = 8g+t (+32)] ----
    const bf16* qrow = qt + (nh * LSEQ + i0 + m0 + l15) * DH;
    bf16x8 a0 = *(const bf16x8*)&qrow[8 * g];
    bf16x8 a1 = *(const bf16x8*)&qrow[8 * g + 32];
    const float inv_norm = 1.0f / norm[n];

    __syncthreads();

    // ---- Phase 1: scores, 24 j-tiles of 16, K-dim 64 = 2 mfma each ----
    f32x4 acc[24];
    #pragma unroll
    for (int jt = 0; jt < 24; jt++) acc[jt] = f32x4{0.f, 0.f, 0.f, 0.f};
    #pragma unroll
    for (int jt = 0; jt < 24; jt++) {
        const bf16* kr = &Kt[(jt * 16 + l15) * 72 + 8 * g];
        bf16x8 b0 = *(const bf16x8*)kr;
        bf16x8 b1 = *(const bf16x8*)(kr + 32);
        acc[jt] = __builtin_amdgcn_mfma_f32_16x16x32_bf16(a0, b0, acc[jt], 0, 0, 0);
        acc[jt] = __builtin_amdgcn_mfma_f32_16x16x32_bf16(a1, b1, acc[jt], 0, 0, 0);
    }

    __syncthreads();   // everyone done reading Kt; smem becomes P

    // ---- softmax over full rows; row i_loc = m0 + 4g + r ----
    const int ib = i0 + m0 + 4 * g;
    float mx[4] = {-1e30f, -1e30f, -1e30f, -1e30f};
    #pragma unroll
    for (int jt = 0; jt < 24; jt++) {
        float ra = radd_s[jt * 16 + l15];
        #pragma unroll
        for (int r = 0; r < 4; r++) {
            int idx = ME - (ib + r) + jt * 16 + l15;
            idx = (idx > 2 * ME - 2) ? (2 * ME - 2) : idx;
            float s = (acc[jt][r] + relp_s[idx] + ra) * inv_norm;
            acc[jt][r] = s;
            mx[r] = fmaxf(mx[r], s);
        }
    }
    #pragma unroll
    for (int r = 0; r < 4; r++) {
        #pragma unroll
        for (int off = 1; off <= 8; off <<= 1)
            mx[r] = fmaxf(mx[r], __shfl_xor(mx[r], off));
    }
    float sm[4] = {0.f, 0.f, 0.f, 0.f};
    #pragma unroll
    for (int jt = 0; jt < 24; jt++) {
        #pragma unroll
        for (int r = 0; r < 4; r++) {
            float e = __expf(acc[jt][r] - mx[r]);
            acc[jt][r] = e;
            sm[r] += e;
        }
    }
    #pragma unroll
    for (int r = 0; r < 4; r++) {
        #pragma unroll
        for (int off = 1; off <= 8; off <<= 1)
            sm[r] += __shfl_xor(sm[r], off);
        sm[r] = 1.0f / sm[r];
    }
    #pragma unroll
    for (int jt = 0; jt < 24; jt++)
        #pragma unroll
        for (int r = 0; r < 4; r++)
            P[(m0 + 4 * g + r) * 400 + jt * 16 + l15] =
                __float2bfloat16(acc[jt][r] * sm[r]);
    // no barrier needed: each wave reads back only its own rows

    // ---- Phase 2: O = P * V^T ----
    f32x4 oacc[4];
    #pragma unroll
    for (int dn = 0; dn < 4; dn++) oacc[dn] = f32x4{0.f, 0.f, 0.f, 0.f};
    #pragma unroll
    for (int jt2 = 0; jt2 < 12; jt2++) {
        bf16x8 a = *(const bf16x8*)&P[(m0 + l15) * 400 + jt2 * 32 + 8 * g];
        #pragma unroll
        for (int dn = 0; dn < 4; dn++) {
            bf16x8 b = *(const bf16x8*)&vg[(size_t)(dn * 16 + l15) * LSEQ + jt2 * 32 + 8 * g];
            oacc[dn] = __builtin_amdgcn_mfma_f32_16x16x32_bf16(a, b, oacc[dn], 0, 0, 0);
        }
    }

    __syncthreads();   // all P reads done; smem becomes O [d][i_loc] stride 72
    #pragma unroll
    for (int dn = 0; dn < 4; dn++)
        #pragma unroll
        for (int r = 0; r < 4; r++)
            O[(dn * 16 + l15) * 72 + m0 + 4 * g + r] = __float2bfloat16(oacc[dn][r]);
    __syncthreads();

    bf16* cg = ctx + ((size_t)n * CHID + h * DH) * LSEQ + i0;
    #pragma unroll
    for (int t = 0; t < 2; t++) {
        int idx = t * 256 + tid;
        int d = idx >> 3, ibk = idx & 7;
        *(uint4*)&cg[(size_t)d * LSEQ + ibk * 8] = *(const uint4*)&O[d * 72 + ibk * 8];
    }
}

// ---------------------------------------------------------------------------
extern "C" void kernel_launch(void* const* d_in, const int* in_sizes, int n_in,
                              void* d_out, int out_size, void* d_ws, size_t ws_size,
                              hipStream_t stream)
{
    const float* x       = (const float*)d_in[0];
    const float* xorg    = (const float*)d_in[1];
    const float* abspos  = (const float*)d_in[2];
    const float* mask    = (const float*)d_in[3];
    const float* norm    = (const float*)d_in[4];
    const float* qkpos   = (const float*)d_in[5];
    const float* qkorg   = (const float*)d_in[6];
    const float* vorg    = (const float*)d_in[7];
    const float* relpos  = (const float*)d_in[8];
    const float* gate_w  = (const float*)d_in[9];
    const float* gate_b  = (const float*)d_in[10];
    const float* q_w     = (const float*)d_in[11];
    const float* k_w     = (const float*)d_in[12];
    const float* v_w     = (const float*)d_in[13];
    const float* dense_w = (const float*)d_in[14];
    const float* dense_b = (const float*)d_in[15];
    float* out = (float*)d_out;

    const size_t TEN = (size_t)N_B * CHID * LSEQ * sizeof(bf16);  // 6291456 B
    char* ws = (char*)d_ws;
    bf16*  qb   = (bf16*)(ws);               // transposed [n][h][i][d]
    bf16*  kb   = (bf16*)(ws + TEN);         // transposed [n][h][j][d]
    bf16*  vb   = (bf16*)(ws + 2 * TEN);     // natural [n][c][l]
    bf16*  ctx  = (bf16*)(ws + 3 * TEN);     // natural [n][c][l]
    float* gate = (float*)(ws + 4 * TEN);

    dim3 gg(LSEQ / 64, CHID / 64, N_B);
    gemm_kernel<0, 1><<<gg, 256, 0, stream>>>(q_w, x, xorg, abspos, qkorg, qkpos,
                                              nullptr, nullptr, qb, nullptr);
    gemm_kernel<0, 1><<<gg, 256, 0, stream>>>(k_w, x, xorg, abspos, qkorg, qkpos,
                                              nullptr, nullptr, kb, nullptr);
    gemm_kernel<1, 0><<<gg, 256, 0, stream>>>(v_w, x, xorg, abspos, vorg, nullptr,
                                              nullptr, nullptr, vb, nullptr);
    gate_kernel<<<dim3(NH, N_B), 384, 0, stream>>>(x, gate_w, gate_b, gate);
    attn2_kernel<<<dim3(LSEQ / 64, NH, N_B), 256, 0, stream>>>(qb, kb, vb, gate,
                                                               mask, norm, relpos, ctx);
    gemm_kernel<2, 0><<<gg, 256, 0, stream>>>(dense_w, nullptr, nullptr, nullptr,
                                              nullptr, nullptr, ctx, dense_b, nullptr, out);
}

// Round 5
// 287.495 us; speedup vs baseline: 3.1951x; 1.4671x over previous
//
#include <hip/hip_runtime.h>
#include <hip/hip_bf16.h>

#define N_B   16
#define CIO   512
#define LSEQ  384
#define DH    64
#define NH    8
#define CHID  512
#define ME    384
#define DG    8

typedef __hip_bfloat16 bf16;
typedef __attribute__((ext_vector_type(8))) short bf16x8;
typedef __attribute__((ext_vector_type(4))) float f32x4;

__device__ __forceinline__ float b2f(bf16 v) { return __bfloat162float(v); }
__device__ __forceinline__ unsigned short f2bs(float f) {
    union { bf16 b; unsigned short u; } cv; cv.b = __float2bfloat16(f); return cv.u;
}

// ---------------------------------------------------------------------------
// wconv: cast 4 weight matrices (512x512 fp32) to bf16. 8 elems/thread.
// ---------------------------------------------------------------------------
__launch_bounds__(256)
__global__ void wconv_kernel(const float* __restrict__ w0, const float* __restrict__ w1,
                             const float* __restrict__ w2, const float* __restrict__ w3,
                             bf16* __restrict__ d0, bf16* __restrict__ d1,
                             bf16* __restrict__ d2, bf16* __restrict__ d3)
{
    int e = (blockIdx.x * 256 + threadIdx.x) * 8;
    int which = e >> 18;                  // 262144 elems per matrix
    int off = e & ((1 << 18) - 1);
    const float* s = which == 0 ? w0 : which == 1 ? w1 : which == 2 ? w2 : w3;
    bf16* d       = which == 0 ? d0 : which == 1 ? d1 : which == 2 ? d2 : d3;
    float4 f0 = *(const float4*)&s[off];
    float4 f1 = *(const float4*)&s[off + 4];
    unsigned short u[8] = {f2bs(f0.x), f2bs(f0.y), f2bs(f0.z), f2bs(f0.w),
                           f2bs(f1.x), f2bs(f1.y), f2bs(f1.z), f2bs(f1.w)};
    *(uint4*)&d[off] = *(uint4*)u;
}

// ---------------------------------------------------------------------------
// prep: X1 = x + qkorg*xorg + qkpos*abspos, X0 = x + vorg*xorg (fp32 math),
// write both bf16 TRANSPOSED [n][l][c]. 64c x 64l tile per block via LDS.
// ---------------------------------------------------------------------------
__launch_bounds__(256)
__global__ void prep_kernel(const float* __restrict__ x, const float* __restrict__ xorg,
                            const float* __restrict__ abspos,
                            const float* __restrict__ qkorg, const float* __restrict__ qkpos,
                            const float* __restrict__ vorg,
                            bf16* __restrict__ x1t, bf16* __restrict__ x0t)
{
    __shared__ bf16 T1[64 * 72], T0[64 * 72];   // [l][c], rows padded to 72 (144B, 16B-aligned)
    __shared__ float r0[64], r1[64], r2[64];
    const int tid = threadIdx.x;
    const int c0 = blockIdx.x * 64;
    const int l0 = blockIdx.y * 64;
    const int n  = blockIdx.z;
    if (tid < 64) {
        int gidx = (c0 + tid) >> 3;
        r0[tid] = vorg[gidx];
        r1[tid] = qkorg[gidx];
        r2[tid] = qkpos[gidx];
    }
    __syncthreads();
    const int l = tid & 63, cs = tid >> 6;
    #pragma unroll
    for (int r = 0; r < 16; r++) {
        int cl = r * 4 + cs;
        size_t gi = ((size_t)n * CIO + c0 + cl) * LSEQ + l0 + l;
        float xv = x[gi], xo = xorg[gi];
        T0[l * 72 + cl] = __float2bfloat16(xv + r0[cl] * xo);
        T1[l * 72 + cl] = __float2bfloat16(xv + r1[cl] * xo + r2[cl] * abspos[gi]);
    }
    __syncthreads();
    #pragma unroll
    for (int t = 0; t < 2; t++) {
        int idx = t * 256 + tid;
        int lr = idx >> 3, u = idx & 7;
        size_t go = ((size_t)n * LSEQ + l0 + lr) * CIO + c0 + u * 8;
        *(uint4*)&x1t[go] = *(const uint4*)&T1[lr * 72 + u * 8];
        *(uint4*)&x0t[go] = *(const uint4*)&T0[lr * 72 + u * 8];
    }
}

// ---------------------------------------------------------------------------
// MFMA GEMM: y[n,o,l] = sum_c W[o,c] * Xt[n,l,c].  256 thr = 4 waves.
// Block tile 64(o) x 128(l); wave w owns l-subtile 32 (full 64 o).
// No LDS in K-loop: A-frags direct from W rows, B-frags direct from Xt rows.
// MODE 0: out bf16 transposed [n][h=o0/64][l][d]   (qk for attention)
// MODE 1: out bf16 natural [n][o][l]               (v)
// MODE 2: out fp32 natural + bias                  (dense)
// ---------------------------------------------------------------------------
template<int MODE>
__launch_bounds__(256)
__global__ void mgemm_kernel(const bf16* __restrict__ Wb,   // [512][512]
                             const bf16* __restrict__ Bt,   // [n][384][512]
                             const float* __restrict__ bias,
                             bf16* __restrict__ outb,
                             float* __restrict__ outf)
{
    constexpr int SBYTES = (MODE == 2) ? 64 * 132 * 4 : (MODE == 0 ? 128 * 72 * 2 : 64 * 136 * 2);
    __shared__ __align__(16) char smem[SBYTES];
    const int tid = threadIdx.x;
    const int lane = tid & 63, w = tid >> 6;
    const int l15 = lane & 15, g = lane >> 4;
    const int l0 = blockIdx.x * 128;
    const int o0 = blockIdx.y * 64;
    const int n  = blockIdx.z;

    f32x4 acc[4][2];
    #pragma unroll
    for (int mt = 0; mt < 4; mt++)
        #pragma unroll
        for (int jt = 0; jt < 2; jt++) acc[mt][jt] = f32x4{0.f, 0.f, 0.f, 0.f};

    const bf16* arow = Wb + (size_t)(o0 + l15) * CIO + 8 * g;
    const bf16* brow = Bt + ((size_t)n * LSEQ + l0 + w * 32 + l15) * CIO + 8 * g;

    #pragma unroll 4
    for (int k0 = 0; k0 < CIO; k0 += 32) {
        bf16x8 a[4], b[2];
        #pragma unroll
        for (int mt = 0; mt < 4; mt++)
            a[mt] = *(const bf16x8*)&arow[(size_t)mt * 16 * CIO + k0];
        #pragma unroll
        for (int jt = 0; jt < 2; jt++)
            b[jt] = *(const bf16x8*)&brow[(size_t)jt * 16 * CIO + k0];
        #pragma unroll
        for (int mt = 0; mt < 4; mt++)
            #pragma unroll
            for (int jt = 0; jt < 2; jt++)
                acc[mt][jt] = __builtin_amdgcn_mfma_f32_16x16x32_bf16(a[mt], b[jt], acc[mt][jt], 0, 0, 0);
    }

    // lane holds D[o = o0+mt*16+4g+r][l = l0+w*32+jt*16+l15]
    if (MODE == 0) {
        bf16* S = (bf16*)smem;   // [128 l][72]
        #pragma unroll
        for (int mt = 0; mt < 4; mt++)
            #pragma unroll
            for (int jt = 0; jt < 2; jt++)
                #pragma unroll
                for (int r = 0; r < 4; r++)
                    S[(w * 32 + jt * 16 + l15) * 72 + mt * 16 + 4 * g + r] =
                        __float2bfloat16(acc[mt][jt][r]);
        __syncthreads();
        bf16* og = outb + ((size_t)n * NH + (o0 >> 6)) * LSEQ * DH + (size_t)l0 * DH;
        #pragma unroll
        for (int t = 0; t < 4; t++) {
            int idx = t * 256 + tid;
            int lr = idx >> 3, u = idx & 7;
            *(uint4*)&og[(size_t)lr * DH + u * 8] = *(const uint4*)&S[lr * 72 + u * 8];
        }
    } else if (MODE == 1) {
        bf16* S = (bf16*)smem;   // [64 o][136]
        #pragma unroll
        for (int mt = 0; mt < 4; mt++)
            #pragma unroll
            for (int jt = 0; jt < 2; jt++)
                #pragma unroll
                for (int r = 0; r < 4; r++)
                    S[(mt * 16 + 4 * g + r) * 136 + w * 32 + jt * 16 + l15] =
                        __float2bfloat16(acc[mt][jt][r]);
        __syncthreads();
        bf16* og = outb + ((size_t)n * CHID + o0) * LSEQ + l0;
        #pragma unroll
        for (int t = 0; t < 4; t++) {
            int idx = t * 256 + tid;
            int orow = idx >> 4, u = idx & 15;
            *(uint4*)&og[(size_t)orow * LSEQ + u * 8] = *(const uint4*)&S[orow * 136 + u * 8];
        }
    } else {
        float* S = (float*)smem; // [64 o][132]
        #pragma unroll
        for (int mt = 0; mt < 4; mt++) {
            #pragma unroll
            for (int r = 0; r < 4; r++) {
                float bv = bias[o0 + mt * 16 + 4 * g + r];
                #pragma unroll
                for (int jt = 0; jt < 2; jt++)
                    S[(mt * 16 + 4 * g + r) * 132 + w * 32 + jt * 16 + l15] =
                        acc[mt][jt][r] + bv;
            }
        }
        __syncthreads();
        float* og = outf + ((size_t)n * CHID + o0) * LSEQ + l0;
        #pragma unroll
        for (int t = 0; t < 8; t++) {
            int idx = t * 256 + tid;
            int orow = idx >> 5, u = idx & 31;
            *(uint4*)&og[(size_t)orow * LSEQ + u * 4] = *(const uint4*)&S[orow * 132 + u * 4];
        }
    }
}

// ---------------------------------------------------------------------------
// gate[n,h,l] = sum_c gate_w[h,c] * x[n,c,l] + gate_b[h]     (raw x!)
// ---------------------------------------------------------------------------
__launch_bounds__(384)
__global__ void gate_kernel(const float* __restrict__ x,
                            const float* __restrict__ gw,
                            const float* __restrict__ gb,
                            float* __restrict__ gate)
{
    __shared__ float w[CIO];
    const int h = blockIdx.x, n = blockIdx.y;
    const int tid = threadIdx.x;   // = l
    for (int c = tid; c < CIO; c += 384) w[c] = gw[h * CIO + c];
    __syncthreads();
    float s = gb[h];
    const float* xp = x + (size_t)n * CIO * LSEQ + tid;
    #pragma unroll 4
    for (int c = 0; c < CIO; c++) s += w[c] * xp[(size_t)c * LSEQ];
    gate[((size_t)n * NH + h) * LSEQ + tid] = s;
}

// ---------------------------------------------------------------------------
// MFMA attention: block = (n, h, 64-query tile), 256 thr = 4 waves.
// Writes ctx TRANSPOSED: ctxt[n][i][c=h*64+d]  (B-layout for dense MFMA GEMM)
// ---------------------------------------------------------------------------
__launch_bounds__(256)
__global__ void attn2_kernel(const bf16* __restrict__ qt,   // [n][h][i][d]
                             const bf16* __restrict__ kt,   // [n][h][j][d]
                             const bf16* __restrict__ v,    // [n][h*64+d][j]
                             const float* __restrict__ gate,
                             const float* __restrict__ mask,
                             const float* __restrict__ norm,
                             const float* __restrict__ relpos,
                             bf16* __restrict__ ctxt)
{
    __shared__ __align__(16) char smem[55296];   // Kt[384][72] | P[64][400] | O[64][72]
    __shared__ float relp_s[2 * ME - 1];
    __shared__ float radd_s[LSEQ];

    bf16* Kt = (bf16*)smem;
    bf16* P  = (bf16*)smem;
    bf16* O  = (bf16*)smem;

    const int tid = threadIdx.x;
    const int i0 = blockIdx.x * 64;
    const int h = blockIdx.y, n = blockIdx.z;
    const int lane = tid & 63;
    const int w = tid >> 6;
    const int l15 = lane & 15, g = lane >> 4;
    const int m0 = w * 16;

    const size_t nh = (size_t)n * NH + h;
    const bf16* kt_g = kt + nh * LSEQ * DH;
    const bf16* vg   = v + ((size_t)n * CHID + h * DH) * LSEQ;

    #pragma unroll
    for (int t = 0; t < 12; t++) {
        int idx = t * 256 + tid;
        int j = idx >> 3, u = idx & 7;
        *(uint4*)&Kt[j * 72 + u * 8] = *(const uint4*)&kt_g[j * 64 + u * 8];
    }
    for (int i = tid; i < LSEQ; i += 256)
        radd_s[i] = gate[nh * LSEQ + i] + mask[(size_t)n * LSEQ + i];
    for (int i = tid; i < 2 * ME - 1; i += 256) relp_s[i] = relpos[i];

    const bf16* qrow = qt + (nh * LSEQ + i0 + m0 + l15) * DH;
    bf16x8 a0 = *(const bf16x8*)&qrow[8 * g];
    bf16x8 a1 = *(const bf16x8*)&qrow[8 * g + 32];
    const float inv_norm = 1.0f / norm[n];

    __syncthreads();

    f32x4 acc[24];
    #pragma unroll
    for (int jt = 0; jt < 24; jt++) acc[jt] = f32x4{0.f, 0.f, 0.f, 0.f};
    #pragma unroll
    for (int jt = 0; jt < 24; jt++) {
        const bf16* kr = &Kt[(jt * 16 + l15) * 72 + 8 * g];
        bf16x8 b0 = *(const bf16x8*)kr;
        bf16x8 b1 = *(const bf16x8*)(kr + 32);
        acc[jt] = __builtin_amdgcn_mfma_f32_16x16x32_bf16(a0, b0, acc[jt], 0, 0, 0);
        acc[jt] = __builtin_amdgcn_mfma_f32_16x16x32_bf16(a1, b1, acc[jt], 0, 0, 0);
    }

    __syncthreads();   // Kt reads done; smem becomes P

    const int ib = i0 + m0 + 4 * g;
    float mx[4] = {-1e30f, -1e30f, -1e30f, -1e30f};
    #pragma unroll
    for (int jt = 0; jt < 24; jt++) {
        float ra = radd_s[jt * 16 + l15];
        #pragma unroll
        for (int r = 0; r < 4; r++) {
            int idx = ME - (ib + r) + jt * 16 + l15;
            idx = (idx > 2 * ME - 2) ? (2 * ME - 2) : idx;
            float s = (acc[jt][r] + relp_s[idx] + ra) * inv_norm;
            acc[jt][r] = s;
            mx[r] = fmaxf(mx[r], s);
        }
    }
    #pragma unroll
    for (int r = 0; r < 4; r++)
        #pragma unroll
        for (int off = 1; off <= 8; off <<= 1)
            mx[r] = fmaxf(mx[r], __shfl_xor(mx[r], off));
    float sm[4] = {0.f, 0.f, 0.f, 0.f};
    #pragma unroll
    for (int jt = 0; jt < 24; jt++) {
        #pragma unroll
        for (int r = 0; r < 4; r++) {
            float e = __expf(acc[jt][r] - mx[r]);
            acc[jt][r] = e;
            sm[r] += e;
        }
    }
    #pragma unroll
    for (int r = 0; r < 4; r++) {
        #pragma unroll
        for (int off = 1; off <= 8; off <<= 1)
            sm[r] += __shfl_xor(sm[r], off);
        sm[r] = 1.0f / sm[r];
    }
    #pragma unroll
    for (int jt = 0; jt < 24; jt++)
        #pragma unroll
        for (int r = 0; r < 4; r++)
            P[(m0 + 4 * g + r) * 400 + jt * 16 + l15] =
                __float2bfloat16(acc[jt][r] * sm[r]);
    // each wave reads back only its own rows — no barrier

    f32x4 oacc[4];
    #pragma unroll
    for (int dn = 0; dn < 4; dn++) oacc[dn] = f32x4{0.f, 0.f, 0.f, 0.f};
    #pragma unroll
    for (int jt2 = 0; jt2 < 12; jt2++) {
        bf16x8 a = *(const bf16x8*)&P[(m0 + l15) * 400 + jt2 * 32 + 8 * g];
        #pragma unroll
        for (int dn = 0; dn < 4; dn++) {
            bf16x8 b = *(const bf16x8*)&vg[(size_t)(dn * 16 + l15) * LSEQ + jt2 * 32 + 8 * g];
            oacc[dn] = __builtin_amdgcn_mfma_f32_16x16x32_bf16(a, b, oacc[dn], 0, 0, 0);
        }
    }

    __syncthreads();   // P reads done; smem becomes O [i_loc][72]
    // lane holds O[i = m0+4g+r][d = dn*16+l15]
    #pragma unroll
    for (int dn = 0; dn < 4; dn++)
        #pragma unroll
        for (int r = 0; r < 4; r++)
            O[(m0 + 4 * g + r) * 72 + dn * 16 + l15] = __float2bfloat16(oacc[dn][r]);
    __syncthreads();

    bf16* cg = ctxt + ((size_t)n * LSEQ + i0) * CHID + h * DH;
    #pragma unroll
    for (int t = 0; t < 2; t++) {
        int idx = t * 256 + tid;
        int ir = idx >> 3, u = idx & 7;
        *(uint4*)&cg[(size_t)ir * CHID + u * 8] = *(const uint4*)&O[ir * 72 + u * 8];
    }
}

// ---------------------------------------------------------------------------
extern "C" void kernel_launch(void* const* d_in, const int* in_sizes, int n_in,
                              void* d_out, int out_size, void* d_ws, size_t ws_size,
                              hipStream_t stream)
{
    const float* x       = (const float*)d_in[0];
    const float* xorg    = (const float*)d_in[1];
    const float* abspos  = (const float*)d_in[2];
    const float* mask    = (const float*)d_in[3];
    const float* norm    = (const float*)d_in[4];
    const float* qkpos   = (const float*)d_in[5];
    const float* qkorg   = (const float*)d_in[6];
    const float* vorg    = (const float*)d_in[7];
    const float* relpos  = (const float*)d_in[8];
    const float* gate_w  = (const float*)d_in[9];
    const float* gate_b  = (const float*)d_in[10];
    const float* q_w     = (const float*)d_in[11];
    const float* k_w     = (const float*)d_in[12];
    const float* v_w     = (const float*)d_in[13];
    const float* dense_w = (const float*)d_in[14];
    const float* dense_b = (const float*)d_in[15];
    float* out = (float*)d_out;

    const size_t TEN = (size_t)N_B * CHID * LSEQ * sizeof(bf16);  // 6291456 B
    const size_t WB  = (size_t)CHID * CIO * sizeof(bf16);          // 524288 B
    char* ws = (char*)d_ws;
    bf16*  x1t  = (bf16*)(ws);                 // [n][l][c]; aliased by ctxt later
    bf16*  x0t  = (bf16*)(ws + TEN);           // [n][l][c]
    bf16*  qb   = (bf16*)(ws + 2 * TEN);       // [n][h][i][d]
    bf16*  kb   = (bf16*)(ws + 3 * TEN);       // [n][h][j][d]
    bf16*  vb   = (bf16*)(ws + 4 * TEN);       // [n][c][l]
    bf16*  wqb  = (bf16*)(ws + 5 * TEN);
    bf16*  wkb  = (bf16*)(ws + 5 * TEN + WB);
    bf16*  wvb  = (bf16*)(ws + 5 * TEN + 2 * WB);
    bf16*  wdb  = (bf16*)(ws + 5 * TEN + 3 * WB);
    float* gate = (float*)(ws + 5 * TEN + 4 * WB);
    bf16*  ctxt = x1t;   // x1t dead after q,k GEMMs; attn runs after them

    wconv_kernel<<<512, 256, 0, stream>>>(q_w, k_w, v_w, dense_w, wqb, wkb, wvb, wdb);
    prep_kernel<<<dim3(CIO / 64, LSEQ / 64, N_B), 256, 0, stream>>>(
        x, xorg, abspos, qkorg, qkpos, vorg, x1t, x0t);
    gate_kernel<<<dim3(NH, N_B), 384, 0, stream>>>(x, gate_w, gate_b, gate);

    dim3 gg(LSEQ / 128, CHID / 64, N_B);
    mgemm_kernel<0><<<gg, 256, 0, stream>>>(wqb, x1t, nullptr, qb, nullptr);
    mgemm_kernel<0><<<gg, 256, 0, stream>>>(wkb, x1t, nullptr, kb, nullptr);
    mgemm_kernel<1><<<gg, 256, 0, stream>>>(wvb, x0t, nullptr, vb, nullptr);
    attn2_kernel<<<dim3(LSEQ / 64, NH, N_B), 256, 0, stream>>>(qb, kb, vb, gate,
                                                               mask, norm, relpos, ctxt);
    mgemm_kernel<2><<<gg, 256, 0, stream>>>(wdb, ctxt, dense_b, nullptr, out);
}

// Round 6
// 232.251 us; speedup vs baseline: 3.9552x; 1.2379x over previous
//
#include <hip/hip_runtime.h>
#include <hip/hip_bf16.h>

#define N_B   16
#define CIO   512
#define LSEQ  384
#define DH    64
#define NH    8
#define CHID  512
#define ME    384
#define DG    8

typedef __hip_bfloat16 bf16;
typedef __attribute__((ext_vector_type(8))) short bf16x8;
typedef __attribute__((ext_vector_type(4))) float f32x4;

__device__ __forceinline__ unsigned short f2bs(float f) {
    union { bf16 b; unsigned short u; } cv; cv.b = __float2bfloat16(f); return cv.u;
}

// ---------------------------------------------------------------------------
// wconv: cast 4 weight matrices (512x512 fp32) to bf16. 8 elems/thread.
// ---------------------------------------------------------------------------
__launch_bounds__(256)
__global__ void wconv_kernel(const float* __restrict__ w0, const float* __restrict__ w1,
                             const float* __restrict__ w2, const float* __restrict__ w3,
                             bf16* __restrict__ d0, bf16* __restrict__ d1,
                             bf16* __restrict__ d2, bf16* __restrict__ d3)
{
    int e = (blockIdx.x * 256 + threadIdx.x) * 8;
    int which = e >> 18;                  // 262144 elems per matrix
    int off = e & ((1 << 18) - 1);
    const float* s = which == 0 ? w0 : which == 1 ? w1 : which == 2 ? w2 : w3;
    bf16* d       = which == 0 ? d0 : which == 1 ? d1 : which == 2 ? d2 : d3;
    float4 f0 = *(const float4*)&s[off];
    float4 f1 = *(const float4*)&s[off + 4];
    unsigned short u[8] = {f2bs(f0.x), f2bs(f0.y), f2bs(f0.z), f2bs(f0.w),
                           f2bs(f1.x), f2bs(f1.y), f2bs(f1.z), f2bs(f1.w)};
    *(uint4*)&d[off] = *(uint4*)u;
}

// ---------------------------------------------------------------------------
// prep: X1 = x + qkorg*xorg + qkpos*abspos, X0 = x + vorg*xorg (fp32 math),
// write both bf16 TRANSPOSED [n][l][c]. 64c x 64l tile per block via LDS.
// ALSO: per-c-block partial gate: gpart[cb][n][h][l] = sum_{c in block} gw[h,c]*x[c,l]
// (raw fp32 x, matching reference gate math). No atomics; attn sums the 8 partials.
// ---------------------------------------------------------------------------
__launch_bounds__(256)
__global__ void prep_kernel(const float* __restrict__ x, const float* __restrict__ xorg,
                            const float* __restrict__ abspos,
                            const float* __restrict__ qkorg, const float* __restrict__ qkpos,
                            const float* __restrict__ vorg,
                            const float* __restrict__ gw,
                            bf16* __restrict__ x1t, bf16* __restrict__ x0t,
                            float* __restrict__ gpart)
{
    __shared__ bf16 T1[64 * 72], T0[64 * 72];   // [l][c], rows padded to 72
    __shared__ float Traw[64 * 65];             // [c][l] fp32, stride 65 (2-way=free)
    __shared__ float gws[NH * 64];              // gate_w slice [h][c_local]
    __shared__ float r0[64], r1[64], r2[64];
    const int tid = threadIdx.x;
    const int cb = blockIdx.x;
    const int c0 = cb * 64;
    const int l0 = blockIdx.y * 64;
    const int n  = blockIdx.z;
    if (tid < 64) {
        int gidx = (c0 + tid) >> 3;
        r0[tid] = vorg[gidx];
        r1[tid] = qkorg[gidx];
        r2[tid] = qkpos[gidx];
    }
    for (int t = tid; t < NH * 64; t += 256) {
        int h = t >> 6, c = t & 63;
        gws[t] = gw[h * CIO + c0 + c];
    }
    __syncthreads();
    const int l = tid & 63, cs = tid >> 6;
    #pragma unroll
    for (int r = 0; r < 16; r++) {
        int cl = r * 4 + cs;
        size_t gi = ((size_t)n * CIO + c0 + cl) * LSEQ + l0 + l;
        float xv = x[gi], xo = xorg[gi];
        Traw[cl * 65 + l] = xv;
        T0[l * 72 + cl] = __float2bfloat16(xv + r0[cl] * xo);
        T1[l * 72 + cl] = __float2bfloat16(xv + r1[cl] * xo + r2[cl] * abspos[gi]);
    }
    __syncthreads();
    // gate partials: 512 outputs (h,l); each thread 2. h is wave-uniform (broadcast gws).
    for (int t = tid; t < NH * 64; t += 256) {
        int h = t >> 6, ll = t & 63;
        float s = 0.f;
        #pragma unroll
        for (int c = 0; c < 64; c++) s += gws[h * 64 + c] * Traw[c * 65 + ll];
        gpart[(((size_t)cb * N_B + n) * NH + h) * LSEQ + l0 + ll] = s;
    }
    #pragma unroll
    for (int t = 0; t < 2; t++) {
        int idx = t * 256 + tid;
        int lr = idx >> 3, u = idx & 7;
        size_t go = ((size_t)n * LSEQ + l0 + lr) * CIO + c0 + u * 8;
        *(uint4*)&x1t[go] = *(const uint4*)&T1[lr * 72 + u * 8];
        *(uint4*)&x0t[go] = *(const uint4*)&T0[lr * 72 + u * 8];
    }
}

// ---------------------------------------------------------------------------
// Merged MFMA GEMM for q/k/v: y[n,o,l] = sum_c W[o,c] * Xt[n,l,c].
// 256 thr = 4 waves, tile 64(o) x 128(l). blockIdx.z = which*N_B + n.
// which 0/1 (q/k): out transposed [n][h][l][d]; which 2 (v): natural [n][o][l].
// ---------------------------------------------------------------------------
__launch_bounds__(256)
__global__ void mgemm_qkv_kernel(const bf16* __restrict__ wq, const bf16* __restrict__ wk,
                                 const bf16* __restrict__ wv,
                                 const bf16* __restrict__ x1t, const bf16* __restrict__ x0t,
                                 bf16* __restrict__ qb, bf16* __restrict__ kb,
                                 bf16* __restrict__ vb)
{
    __shared__ __align__(16) char smem[18432];
    const int tid = threadIdx.x;
    const int lane = tid & 63, w = tid >> 6;
    const int l15 = lane & 15, g = lane >> 4;
    const int l0 = blockIdx.x * 128;
    const int o0 = blockIdx.y * 64;
    const int which = blockIdx.z >> 4;
    const int n = blockIdx.z & 15;

    const bf16* Wb = which == 0 ? wq : which == 1 ? wk : wv;
    const bf16* Bt = which == 2 ? x0t : x1t;

    f32x4 acc[4][2];
    #pragma unroll
    for (int mt = 0; mt < 4; mt++)
        #pragma unroll
        for (int jt = 0; jt < 2; jt++) acc[mt][jt] = f32x4{0.f, 0.f, 0.f, 0.f};

    const bf16* arow = Wb + (size_t)(o0 + l15) * CIO + 8 * g;
    const bf16* brow = Bt + ((size_t)n * LSEQ + l0 + w * 32 + l15) * CIO + 8 * g;

    #pragma unroll 4
    for (int k0 = 0; k0 < CIO; k0 += 32) {
        bf16x8 a[4], b[2];
        #pragma unroll
        for (int mt = 0; mt < 4; mt++)
            a[mt] = *(const bf16x8*)&arow[(size_t)mt * 16 * CIO + k0];
        #pragma unroll
        for (int jt = 0; jt < 2; jt++)
            b[jt] = *(const bf16x8*)&brow[(size_t)jt * 16 * CIO + k0];
        #pragma unroll
        for (int mt = 0; mt < 4; mt++)
            #pragma unroll
            for (int jt = 0; jt < 2; jt++)
                acc[mt][jt] = __builtin_amdgcn_mfma_f32_16x16x32_bf16(a[mt], b[jt], acc[mt][jt], 0, 0, 0);
    }

    // lane holds D[o = o0+mt*16+4g+r][l = l0+w*32+jt*16+l15]
    if (which < 2) {
        bf16* S = (bf16*)smem;   // [128 l][72]
        #pragma unroll
        for (int mt = 0; mt < 4; mt++)
            #pragma unroll
            for (int jt = 0; jt < 2; jt++)
                #pragma unroll
                for (int r = 0; r < 4; r++)
                    S[(w * 32 + jt * 16 + l15) * 72 + mt * 16 + 4 * g + r] =
                        __float2bfloat16(acc[mt][jt][r]);
        __syncthreads();
        bf16* outb = which == 0 ? qb : kb;
        bf16* og = outb + ((size_t)n * NH + (o0 >> 6)) * LSEQ * DH + (size_t)l0 * DH;
        #pragma unroll
        for (int t = 0; t < 4; t++) {
            int idx = t * 256 + tid;
            int lr = idx >> 3, u = idx & 7;
            *(uint4*)&og[(size_t)lr * DH + u * 8] = *(const uint4*)&S[lr * 72 + u * 8];
        }
    } else {
        bf16* S = (bf16*)smem;   // [64 o][136]
        #pragma unroll
        for (int mt = 0; mt < 4; mt++)
            #pragma unroll
            for (int jt = 0; jt < 2; jt++)
                #pragma unroll
                for (int r = 0; r < 4; r++)
                    S[(mt * 16 + 4 * g + r) * 136 + w * 32 + jt * 16 + l15] =
                        __float2bfloat16(acc[mt][jt][r]);
        __syncthreads();
        bf16* og = vb + ((size_t)n * CHID + o0) * LSEQ + l0;
        #pragma unroll
        for (int t = 0; t < 4; t++) {
            int idx = t * 256 + tid;
            int orow = idx >> 4, u = idx & 15;
            *(uint4*)&og[(size_t)orow * LSEQ + u * 8] = *(const uint4*)&S[orow * 136 + u * 8];
        }
    }
}

// ---------------------------------------------------------------------------
// Dense MFMA GEMM: out fp32 natural + bias.
// ---------------------------------------------------------------------------
__launch_bounds__(256)
__global__ void mgemm_dense_kernel(const bf16* __restrict__ Wb,
                                   const bf16* __restrict__ Bt,
                                   const float* __restrict__ bias,
                                   float* __restrict__ outf)
{
    __shared__ __align__(16) float S[64 * 132];
    const int tid = threadIdx.x;
    const int lane = tid & 63, w = tid >> 6;
    const int l15 = lane & 15, g = lane >> 4;
    const int l0 = blockIdx.x * 128;
    const int o0 = blockIdx.y * 64;
    const int n  = blockIdx.z;

    f32x4 acc[4][2];
    #pragma unroll
    for (int mt = 0; mt < 4; mt++)
        #pragma unroll
        for (int jt = 0; jt < 2; jt++) acc[mt][jt] = f32x4{0.f, 0.f, 0.f, 0.f};

    const bf16* arow = Wb + (size_t)(o0 + l15) * CIO + 8 * g;
    const bf16* brow = Bt + ((size_t)n * LSEQ + l0 + w * 32 + l15) * CIO + 8 * g;

    #pragma unroll 4
    for (int k0 = 0; k0 < CIO; k0 += 32) {
        bf16x8 a[4], b[2];
        #pragma unroll
        for (int mt = 0; mt < 4; mt++)
            a[mt] = *(const bf16x8*)&arow[(size_t)mt * 16 * CIO + k0];
        #pragma unroll
        for (int jt = 0; jt < 2; jt++)
            b[jt] = *(const bf16x8*)&brow[(size_t)jt * 16 * CIO + k0];
        #pragma unroll
        for (int mt = 0; mt < 4; mt++)
            #pragma unroll
            for (int jt = 0; jt < 2; jt++)
                acc[mt][jt] = __builtin_amdgcn_mfma_f32_16x16x32_bf16(a[mt], b[jt], acc[mt][jt], 0, 0, 0);
    }

    #pragma unroll
    for (int mt = 0; mt < 4; mt++) {
        #pragma unroll
        for (int r = 0; r < 4; r++) {
            float bv = bias[o0 + mt * 16 + 4 * g + r];
            #pragma unroll
            for (int jt = 0; jt < 2; jt++)
                S[(mt * 16 + 4 * g + r) * 132 + w * 32 + jt * 16 + l15] =
                    acc[mt][jt][r] + bv;
        }
    }
    __syncthreads();
    float* og = outf + ((size_t)n * CHID + o0) * LSEQ + l0;
    #pragma unroll
    for (int t = 0; t < 8; t++) {
        int idx = t * 256 + tid;
        int orow = idx >> 5, u = idx & 31;
        *(uint4*)&og[(size_t)orow * LSEQ + u * 4] = *(const uint4*)&S[orow * 132 + u * 4];
    }
}

// ---------------------------------------------------------------------------
// MFMA attention: block = (n, h, 64-query tile), 256 thr = 4 waves.
// Gate comes in as 8 c-block partials (gpart) + gate_b.
// Writes ctx TRANSPOSED: ctxt[n][i][c=h*64+d]  (B-layout for dense MFMA GEMM)
// ---------------------------------------------------------------------------
__launch_bounds__(256)
__global__ void attn2_kernel(const bf16* __restrict__ qt,   // [n][h][i][d]
                             const bf16* __restrict__ kt,   // [n][h][j][d]
                             const bf16* __restrict__ v,    // [n][h*64+d][j]
                             const float* __restrict__ gpart,
                             const float* __restrict__ gb,
                             const float* __restrict__ mask,
                             const float* __restrict__ norm,
                             const float* __restrict__ relpos,
                             bf16* __restrict__ ctxt)
{
    __shared__ __align__(16) char smem[55296];   // Kt[384][72] | P[64][400] | O[64][72]
    __shared__ float relp_s[2 * ME - 1];
    __shared__ float radd_s[LSEQ];

    bf16* Kt = (bf16*)smem;
    bf16* P  = (bf16*)smem;
    bf16* O  = (bf16*)smem;

    const int tid = threadIdx.x;
    const int i0 = blockIdx.x * 64;
    const int h = blockIdx.y, n = blockIdx.z;
    const int lane = tid & 63;
    const int w = tid >> 6;
    const int l15 = lane & 15, g = lane >> 4;
    const int m0 = w * 16;

    const size_t nh = (size_t)n * NH + h;
    const bf16* kt_g = kt + nh * LSEQ * DH;
    const bf16* vg   = v + ((size_t)n * CHID + h * DH) * LSEQ;

    #pragma unroll
    for (int t = 0; t < 12; t++) {
        int idx = t * 256 + tid;
        int j = idx >> 3, u = idx & 7;
        *(uint4*)&Kt[j * 72 + u * 8] = *(const uint4*)&kt_g[j * 64 + u * 8];
    }
    {
        const float gbh = gb[h];
        for (int i = tid; i < LSEQ; i += 256) {
            float s = gbh + mask[(size_t)n * LSEQ + i];
            #pragma unroll
            for (int cb = 0; cb < 8; cb++)
                s += gpart[(((size_t)cb * N_B + n) * NH + h) * LSEQ + i];
            radd_s[i] = s;
        }
    }
    for (int i = tid; i < 2 * ME - 1; i += 256) relp_s[i] = relpos[i];

    const bf16* qrow = qt + (nh * LSEQ + i0 + m0 + l15) * DH;
    bf16x8 a0 = *(const bf16x8*)&qrow[8 * g];
    bf16x8 a1 = *(const bf16x8*)&qrow[8 * g + 32];
    const float inv_norm = 1.0f / norm[n];

    __syncthreads();

    f32x4 acc[24];
    #pragma unroll
    for (int jt = 0; jt < 24; jt++) acc[jt] = f32x4{0.f, 0.f, 0.f, 0.f};
    #pragma unroll
    for (int jt = 0; jt < 24; jt++) {
        const bf16* kr = &Kt[(jt * 16 + l15) * 72 + 8 * g];
        bf16x8 b0 = *(const bf16x8*)kr;
        bf16x8 b1 = *(const bf16x8*)(kr + 32);
        acc[jt] = __builtin_amdgcn_mfma_f32_16x16x32_bf16(a0, b0, acc[jt], 0, 0, 0);
        acc[jt] = __builtin_amdgcn_mfma_f32_16x16x32_bf16(a1, b1, acc[jt], 0, 0, 0);
    }

    __syncthreads();   // Kt reads done; smem becomes P

    const int ib = i0 + m0 + 4 * g;
    float mx[4] = {-1e30f, -1e30f, -1e30f, -1e30f};
    #pragma unroll
    for (int jt = 0; jt < 24; jt++) {
        float ra = radd_s[jt * 16 + l15];
        #pragma unroll
        for (int r = 0; r < 4; r++) {
            int idx = ME - (ib + r) + jt * 16 + l15;
            idx = (idx > 2 * ME - 2) ? (2 * ME - 2) : idx;
            float s = (acc[jt][r] + relp_s[idx] + ra) * inv_norm;
            acc[jt][r] = s;
            mx[r] = fmaxf(mx[r], s);
        }
    }
    #pragma unroll
    for (int r = 0; r < 4; r++)
        #pragma unroll
        for (int off = 1; off <= 8; off <<= 1)
            mx[r] = fmaxf(mx[r], __shfl_xor(mx[r], off));
    float sm[4] = {0.f, 0.f, 0.f, 0.f};
    #pragma unroll
    for (int jt = 0; jt < 24; jt++) {
        #pragma unroll
        for (int r = 0; r < 4; r++) {
            float e = __expf(acc[jt][r] - mx[r]);
            acc[jt][r] = e;
            sm[r] += e;
        }
    }
    #pragma unroll
    for (int r = 0; r < 4; r++) {
        #pragma unroll
        for (int off = 1; off <= 8; off <<= 1)
            sm[r] += __shfl_xor(sm[r], off);
        sm[r] = 1.0f / sm[r];
    }
    #pragma unroll
    for (int jt = 0; jt < 24; jt++)
        #pragma unroll
        for (int r = 0; r < 4; r++)
            P[(m0 + 4 * g + r) * 400 + jt * 16 + l15] =
                __float2bfloat16(acc[jt][r] * sm[r]);
    // each wave reads back only its own rows — no barrier

    f32x4 oacc[4];
    #pragma unroll
    for (int dn = 0; dn < 4; dn++) oacc[dn] = f32x4{0.f, 0.f, 0.f, 0.f};
    #pragma unroll
    for (int jt2 = 0; jt2 < 12; jt2++) {
        bf16x8 a = *(const bf16x8*)&P[(m0 + l15) * 400 + jt2 * 32 + 8 * g];
        #pragma unroll
        for (int dn = 0; dn < 4; dn++) {
            bf16x8 b = *(const bf16x8*)&vg[(size_t)(dn * 16 + l15) * LSEQ + jt2 * 32 + 8 * g];
            oacc[dn] = __builtin_amdgcn_mfma_f32_16x16x32_bf16(a, b, oacc[dn], 0, 0, 0);
        }
    }

    __syncthreads();   // P reads done; smem becomes O [i_loc][72]
    #pragma unroll
    for (int dn = 0; dn < 4; dn++)
        #pragma unroll
        for (int r = 0; r < 4; r++)
            O[(m0 + 4 * g + r) * 72 + dn * 16 + l15] = __float2bfloat16(oacc[dn][r]);
    __syncthreads();

    bf16* cg = ctxt + ((size_t)n * LSEQ + i0) * CHID + h * DH;
    #pragma unroll
    for (int t = 0; t < 2; t++) {
        int idx = t * 256 + tid;
        int ir = idx >> 3, u = idx & 7;
        *(uint4*)&cg[(size_t)ir * CHID + u * 8] = *(const uint4*)&O[ir * 72 + u * 8];
    }
}

// ---------------------------------------------------------------------------
extern "C" void kernel_launch(void* const* d_in, const int* in_sizes, int n_in,
                              void* d_out, int out_size, void* d_ws, size_t ws_size,
                              hipStream_t stream)
{
    const float* x       = (const float*)d_in[0];
    const float* xorg    = (const float*)d_in[1];
    const float* abspos  = (const float*)d_in[2];
    const float* mask    = (const float*)d_in[3];
    const float* norm    = (const float*)d_in[4];
    const float* qkpos   = (const float*)d_in[5];
    const float* qkorg   = (const float*)d_in[6];
    const float* vorg    = (const float*)d_in[7];
    const float* relpos  = (const float*)d_in[8];
    const float* gate_w  = (const float*)d_in[9];
    const float* gate_b  = (const float*)d_in[10];
    const float* q_w     = (const float*)d_in[11];
    const float* k_w     = (const float*)d_in[12];
    const float* v_w     = (const float*)d_in[13];
    const float* dense_w = (const float*)d_in[14];
    const float* dense_b = (const float*)d_in[15];
    float* out = (float*)d_out;

    const size_t TEN = (size_t)N_B * CHID * LSEQ * sizeof(bf16);  // 6291456 B
    const size_t WB  = (size_t)CHID * CIO * sizeof(bf16);          // 524288 B
    char* ws = (char*)d_ws;
    bf16*  x1t  = (bf16*)(ws);                 // [n][l][c]; aliased by ctxt later
    bf16*  x0t  = (bf16*)(ws + TEN);           // [n][l][c]
    bf16*  qb   = (bf16*)(ws + 2 * TEN);       // [n][h][i][d]
    bf16*  kb   = (bf16*)(ws + 3 * TEN);       // [n][h][j][d]
    bf16*  vb   = (bf16*)(ws + 4 * TEN);       // [n][c][l]
    bf16*  wqb  = (bf16*)(ws + 5 * TEN);
    bf16*  wkb  = (bf16*)(ws + 5 * TEN + WB);
    bf16*  wvb  = (bf16*)(ws + 5 * TEN + 2 * WB);
    bf16*  wdb  = (bf16*)(ws + 5 * TEN + 3 * WB);
    float* gpart = (float*)(ws + 5 * TEN + 4 * WB);  // [8][16][8][384] fp32, 1.57 MB
    bf16*  ctxt = x1t;   // x1t dead after q,k GEMMs; attn runs after them

    wconv_kernel<<<512, 256, 0, stream>>>(q_w, k_w, v_w, dense_w, wqb, wkb, wvb, wdb);
    prep_kernel<<<dim3(CIO / 64, LSEQ / 64, N_B), 256, 0, stream>>>(
        x, xorg, abspos, qkorg, qkpos, vorg, gate_w, x1t, x0t, gpart);
    mgemm_qkv_kernel<<<dim3(LSEQ / 128, CHID / 64, 3 * N_B), 256, 0, stream>>>(
        wqb, wkb, wvb, x1t, x0t, qb, kb, vb);
    attn2_kernel<<<dim3(LSEQ / 64, NH, N_B), 256, 0, stream>>>(qb, kb, vb, gpart, gate_b,
                                                               mask, norm, relpos, ctxt);
    mgemm_dense_kernel<<<dim3(LSEQ / 128, CHID / 64, N_B), 256, 0, stream>>>(
        wdb, ctxt, dense_b, out);
}

// Round 7
// 228.706 us; speedup vs baseline: 4.0165x; 1.0155x over previous
//
#include <hip/hip_runtime.h>
#include <hip/hip_bf16.h>

#define N_B   16
#define CIO   512
#define LSEQ  384
#define DH    64
#define NH    8
#define CHID  512
#define ME    384
#define DG    8

typedef __hip_bfloat16 bf16;
typedef __attribute__((ext_vector_type(8))) short bf16x8;
typedef __attribute__((ext_vector_type(4))) float f32x4;

__device__ __forceinline__ unsigned short f2bs(float f) {
    union { bf16 b; unsigned short u; } cv; cv.b = __float2bfloat16(f); return cv.u;
}

// ---------------------------------------------------------------------------
// wconv: cast 4 weight matrices (512x512 fp32) to bf16. 8 elems/thread.
// ---------------------------------------------------------------------------
__launch_bounds__(256)
__global__ void wconv_kernel(const float* __restrict__ w0, const float* __restrict__ w1,
                             const float* __restrict__ w2, const float* __restrict__ w3,
                             bf16* __restrict__ d0, bf16* __restrict__ d1,
                             bf16* __restrict__ d2, bf16* __restrict__ d3)
{
    int e = (blockIdx.x * 256 + threadIdx.x) * 8;
    int which = e >> 18;                  // 262144 elems per matrix
    int off = e & ((1 << 18) - 1);
    const float* s = which == 0 ? w0 : which == 1 ? w1 : which == 2 ? w2 : w3;
    bf16* d       = which == 0 ? d0 : which == 1 ? d1 : which == 2 ? d2 : d3;
    float4 f0 = *(const float4*)&s[off];
    float4 f1 = *(const float4*)&s[off + 4];
    unsigned short u[8] = {f2bs(f0.x), f2bs(f0.y), f2bs(f0.z), f2bs(f0.w),
                           f2bs(f1.x), f2bs(f1.y), f2bs(f1.z), f2bs(f1.w)};
    *(uint4*)&d[off] = *(uint4*)u;
}

// ---------------------------------------------------------------------------
// prep: X1 = x + qkorg*xorg + qkpos*abspos, X0 = x + vorg*xorg (fp32 math),
// write both bf16 TRANSPOSED [n][l][c]. 64c x 64l tile per block via LDS.
// ALSO: per-c-block partial gate into gpart[cb][n][h][l] (no atomics).
// ---------------------------------------------------------------------------
__launch_bounds__(256)
__global__ void prep_kernel(const float* __restrict__ x, const float* __restrict__ xorg,
                            const float* __restrict__ abspos,
                            const float* __restrict__ qkorg, const float* __restrict__ qkpos,
                            const float* __restrict__ vorg,
                            const float* __restrict__ gw,
                            bf16* __restrict__ x1t, bf16* __restrict__ x0t,
                            float* __restrict__ gpart)
{
    __shared__ bf16 T1[64 * 72], T0[64 * 72];   // [l][c], rows padded to 72
    __shared__ float Traw[64 * 65];             // [c][l] fp32, stride 65
    __shared__ float gws[NH * 64];              // gate_w slice [h][c_local]
    __shared__ float r0[64], r1[64], r2[64];
    const int tid = threadIdx.x;
    const int cb = blockIdx.x;
    const int c0 = cb * 64;
    const int l0 = blockIdx.y * 64;
    const int n  = blockIdx.z;
    if (tid < 64) {
        int gidx = (c0 + tid) >> 3;
        r0[tid] = vorg[gidx];
        r1[tid] = qkorg[gidx];
        r2[tid] = qkpos[gidx];
    }
    for (int t = tid; t < NH * 64; t += 256) {
        int h = t >> 6, c = t & 63;
        gws[t] = gw[h * CIO + c0 + c];
    }
    __syncthreads();
    const int l = tid & 63, cs = tid >> 6;
    #pragma unroll
    for (int r = 0; r < 16; r++) {
        int cl = r * 4 + cs;
        size_t gi = ((size_t)n * CIO + c0 + cl) * LSEQ + l0 + l;
        float xv = x[gi], xo = xorg[gi];
        Traw[cl * 65 + l] = xv;
        T0[l * 72 + cl] = __float2bfloat16(xv + r0[cl] * xo);
        T1[l * 72 + cl] = __float2bfloat16(xv + r1[cl] * xo + r2[cl] * abspos[gi]);
    }
    __syncthreads();
    for (int t = tid; t < NH * 64; t += 256) {
        int h = t >> 6, ll = t & 63;
        float s = 0.f;
        #pragma unroll
        for (int c = 0; c < 64; c++) s += gws[h * 64 + c] * Traw[c * 65 + ll];
        gpart[(((size_t)cb * N_B + n) * NH + h) * LSEQ + l0 + ll] = s;
    }
    #pragma unroll
    for (int t = 0; t < 2; t++) {
        int idx = t * 256 + tid;
        int lr = idx >> 3, u = idx & 7;
        size_t go = ((size_t)n * LSEQ + l0 + lr) * CIO + c0 + u * 8;
        *(uint4*)&x1t[go] = *(const uint4*)&T1[lr * 72 + u * 8];
        *(uint4*)&x0t[go] = *(const uint4*)&T0[lr * 72 + u * 8];
    }
}

// ---------------------------------------------------------------------------
// Merged MFMA GEMM for q/k/v. 1D grid of 1152, XCD-swizzled:
// slice (which*16+n) pinned to id%8 residue so each XCD's L2 holds only its
// 4 B-tensors (1.6 MB) + weights (1.5 MB) < 4 MB.  Tile 64(o) x 128(l).
// ---------------------------------------------------------------------------
__launch_bounds__(256)
__global__ void mgemm_qkv_kernel(const bf16* __restrict__ wq, const bf16* __restrict__ wk,
                                 const bf16* __restrict__ wv,
                                 const bf16* __restrict__ x1t, const bf16* __restrict__ x0t,
                                 bf16* __restrict__ qb, bf16* __restrict__ kb,
                                 bf16* __restrict__ vb)
{
    __shared__ __align__(16) char smem[18432];
    const int tid = threadIdx.x;
    const int lane = tid & 63, w = tid >> 6;
    const int l15 = lane & 15, g = lane >> 4;
    // XCD swizzle: id%8 = residue, 6 slices/residue, 24 blocks/slice
    const int Bid = blockIdx.x;
    const int rres = Bid & 7, qq = Bid >> 3;          // qq 0..143
    const int slice = rres + 8 * (qq / 24);           // 0..47 = which*16+n
    const int within = qq % 24;
    const int which = slice >> 4;
    const int n = slice & 15;
    const int l0 = (within % 3) * 128;
    const int o0 = (within / 3) * 64;

    const bf16* Wb = which == 0 ? wq : which == 1 ? wk : wv;
    const bf16* Bt = which == 2 ? x0t : x1t;

    f32x4 acc[4][2];
    #pragma unroll
    for (int mt = 0; mt < 4; mt++)
        #pragma unroll
        for (int jt = 0; jt < 2; jt++) acc[mt][jt] = f32x4{0.f, 0.f, 0.f, 0.f};

    const bf16* arow = Wb + (size_t)(o0 + l15) * CIO + 8 * g;
    const bf16* brow = Bt + ((size_t)n * LSEQ + l0 + w * 32 + l15) * CIO + 8 * g;

    #pragma unroll 4
    for (int k0 = 0; k0 < CIO; k0 += 32) {
        bf16x8 a[4], b[2];
        #pragma unroll
        for (int mt = 0; mt < 4; mt++)
            a[mt] = *(const bf16x8*)&arow[(size_t)mt * 16 * CIO + k0];
        #pragma unroll
        for (int jt = 0; jt < 2; jt++)
            b[jt] = *(const bf16x8*)&brow[(size_t)jt * 16 * CIO + k0];
        #pragma unroll
        for (int mt = 0; mt < 4; mt++)
            #pragma unroll
            for (int jt = 0; jt < 2; jt++)
                acc[mt][jt] = __builtin_amdgcn_mfma_f32_16x16x32_bf16(a[mt], b[jt], acc[mt][jt], 0, 0, 0);
    }

    // lane holds D[o = o0+mt*16+4g+r][l = l0+w*32+jt*16+l15]
    if (which < 2) {
        bf16* S = (bf16*)smem;   // [128 l][72]
        #pragma unroll
        for (int mt = 0; mt < 4; mt++)
            #pragma unroll
            for (int jt = 0; jt < 2; jt++)
                #pragma unroll
                for (int r = 0; r < 4; r++)
                    S[(w * 32 + jt * 16 + l15) * 72 + mt * 16 + 4 * g + r] =
                        __float2bfloat16(acc[mt][jt][r]);
        __syncthreads();
        bf16* outb = which == 0 ? qb : kb;
        bf16* og = outb + ((size_t)n * NH + (o0 >> 6)) * LSEQ * DH + (size_t)l0 * DH;
        #pragma unroll
        for (int t = 0; t < 4; t++) {
            int idx = t * 256 + tid;
            int lr = idx >> 3, u = idx & 7;
            *(uint4*)&og[(size_t)lr * DH + u * 8] = *(const uint4*)&S[lr * 72 + u * 8];
        }
    } else {
        bf16* S = (bf16*)smem;   // [64 o][136]
        #pragma unroll
        for (int mt = 0; mt < 4; mt++)
            #pragma unroll
            for (int jt = 0; jt < 2; jt++)
                #pragma unroll
                for (int r = 0; r < 4; r++)
                    S[(mt * 16 + 4 * g + r) * 136 + w * 32 + jt * 16 + l15] =
                        __float2bfloat16(acc[mt][jt][r]);
        __syncthreads();
        bf16* og = vb + ((size_t)n * CHID + o0) * LSEQ + l0;
        #pragma unroll
        for (int t = 0; t < 4; t++) {
            int idx = t * 256 + tid;
            int orow = idx >> 4, u = idx & 15;
            *(uint4*)&og[(size_t)orow * LSEQ + u * 8] = *(const uint4*)&S[orow * 136 + u * 8];
        }
    }
}

// ---------------------------------------------------------------------------
// Dense MFMA GEMM, XCD-swizzled 1D grid of 384 (slice = n, 2 n per residue).
// ---------------------------------------------------------------------------
__launch_bounds__(256)
__global__ void mgemm_dense_kernel(const bf16* __restrict__ Wb,
                                   const bf16* __restrict__ Bt,
                                   const float* __restrict__ bias,
                                   float* __restrict__ outf)
{
    __shared__ __align__(16) float S[64 * 132];
    const int tid = threadIdx.x;
    const int lane = tid & 63, w = tid >> 6;
    const int l15 = lane & 15, g = lane >> 4;
    const int Bid = blockIdx.x;
    const int rres = Bid & 7, qq = Bid >> 3;   // qq 0..47
    const int n = rres + 8 * (qq / 24);        // 0..15
    const int within = qq % 24;
    const int l0 = (within % 3) * 128;
    const int o0 = (within / 3) * 64;

    f32x4 acc[4][2];
    #pragma unroll
    for (int mt = 0; mt < 4; mt++)
        #pragma unroll
        for (int jt = 0; jt < 2; jt++) acc[mt][jt] = f32x4{0.f, 0.f, 0.f, 0.f};

    const bf16* arow = Wb + (size_t)(o0 + l15) * CIO + 8 * g;
    const bf16* brow = Bt + ((size_t)n * LSEQ + l0 + w * 32 + l15) * CIO + 8 * g;

    #pragma unroll 4
    for (int k0 = 0; k0 < CIO; k0 += 32) {
        bf16x8 a[4], b[2];
        #pragma unroll
        for (int mt = 0; mt < 4; mt++)
            a[mt] = *(const bf16x8*)&arow[(size_t)mt * 16 * CIO + k0];
        #pragma unroll
        for (int jt = 0; jt < 2; jt++)
            b[jt] = *(const bf16x8*)&brow[(size_t)jt * 16 * CIO + k0];
        #pragma unroll
        for (int mt = 0; mt < 4; mt++)
            #pragma unroll
            for (int jt = 0; jt < 2; jt++)
                acc[mt][jt] = __builtin_amdgcn_mfma_f32_16x16x32_bf16(a[mt], b[jt], acc[mt][jt], 0, 0, 0);
    }

    #pragma unroll
    for (int mt = 0; mt < 4; mt++) {
        #pragma unroll
        for (int r = 0; r < 4; r++) {
            float bv = bias[o0 + mt * 16 + 4 * g + r];
            #pragma unroll
            for (int jt = 0; jt < 2; jt++)
                S[(mt * 16 + 4 * g + r) * 132 + w * 32 + jt * 16 + l15] =
                    acc[mt][jt][r] + bv;
        }
    }
    __syncthreads();
    float* og = outf + ((size_t)n * CHID + o0) * LSEQ + l0;
    #pragma unroll
    for (int t = 0; t < 8; t++) {
        int idx = t * 256 + tid;
        int orow = idx >> 5, u = idx & 31;
        *(uint4*)&og[(size_t)orow * LSEQ + u * 4] = *(const uint4*)&S[orow * 132 + u * 4];
    }
}

// ---------------------------------------------------------------------------
// MFMA attention, XCD-swizzled 1D grid of 768: residue = h, so each XCD's L2
// holds one head's q/k/v across all n (~1.7 MB).
// ---------------------------------------------------------------------------
__launch_bounds__(256)
__global__ void attn2_kernel(const bf16* __restrict__ qt,   // [n][h][i][d]
                             const bf16* __restrict__ kt,   // [n][h][j][d]
                             const bf16* __restrict__ v,    // [n][h*64+d][j]
                             const float* __restrict__ gpart,
                             const float* __restrict__ gb,
                             const float* __restrict__ mask,
                             const float* __restrict__ norm,
                             const float* __restrict__ relpos,
                             bf16* __restrict__ ctxt)
{
    __shared__ __align__(16) char smem[55296];   // Kt[384][72] | P[64][400] | O[64][72]
    __shared__ float relp_s[2 * ME - 1];
    __shared__ float radd_s[LSEQ];

    bf16* Kt = (bf16*)smem;
    bf16* P  = (bf16*)smem;
    bf16* O  = (bf16*)smem;

    const int tid = threadIdx.x;
    const int Bid = blockIdx.x;
    const int h = Bid & 7, qq = Bid >> 3;   // qq 0..95
    const int n = qq / 6;
    const int i0 = (qq % 6) * 64;
    const int lane = tid & 63;
    const int w = tid >> 6;
    const int l15 = lane & 15, g = lane >> 4;
    const int m0 = w * 16;

    const size_t nh = (size_t)n * NH + h;
    const bf16* kt_g = kt + nh * LSEQ * DH;
    const bf16* vg   = v + ((size_t)n * CHID + h * DH) * LSEQ;

    #pragma unroll
    for (int t = 0; t < 12; t++) {
        int idx = t * 256 + tid;
        int j = idx >> 3, u = idx & 7;
        *(uint4*)&Kt[j * 72 + u * 8] = *(const uint4*)&kt_g[j * 64 + u * 8];
    }
    {
        const float gbh = gb[h];
        for (int i = tid; i < LSEQ; i += 256) {
            float s = gbh + mask[(size_t)n * LSEQ + i];
            #pragma unroll
            for (int cb = 0; cb < 8; cb++)
                s += gpart[(((size_t)cb * N_B + n) * NH + h) * LSEQ + i];
            radd_s[i] = s;
        }
    }
    for (int i = tid; i < 2 * ME - 1; i += 256) relp_s[i] = relpos[i];

    const bf16* qrow = qt + (nh * LSEQ + i0 + m0 + l15) * DH;
    bf16x8 a0 = *(const bf16x8*)&qrow[8 * g];
    bf16x8 a1 = *(const bf16x8*)&qrow[8 * g + 32];
    const float inv_norm = 1.0f / norm[n];

    __syncthreads();

    f32x4 acc[24];
    #pragma unroll
    for (int jt = 0; jt < 24; jt++) acc[jt] = f32x4{0.f, 0.f, 0.f, 0.f};
    #pragma unroll
    for (int jt = 0; jt < 24; jt++) {
        const bf16* kr = &Kt[(jt * 16 + l15) * 72 + 8 * g];
        bf16x8 b0 = *(const bf16x8*)kr;
        bf16x8 b1 = *(const bf16x8*)(kr + 32);
        acc[jt] = __builtin_amdgcn_mfma_f32_16x16x32_bf16(a0, b0, acc[jt], 0, 0, 0);
        acc[jt] = __builtin_amdgcn_mfma_f32_16x16x32_bf16(a1, b1, acc[jt], 0, 0, 0);
    }

    __syncthreads();   // Kt reads done; smem becomes P

    const int ib = i0 + m0 + 4 * g;
    float mx[4] = {-1e30f, -1e30f, -1e30f, -1e30f};
    #pragma unroll
    for (int jt = 0; jt < 24; jt++) {
        float ra = radd_s[jt * 16 + l15];
        #pragma unroll
        for (int r = 0; r < 4; r++) {
            int idx = ME - (ib + r) + jt * 16 + l15;
            idx = (idx > 2 * ME - 2) ? (2 * ME - 2) : idx;
            float s = (acc[jt][r] + relp_s[idx] + ra) * inv_norm;
            acc[jt][r] = s;
            mx[r] = fmaxf(mx[r], s);
        }
    }
    #pragma unroll
    for (int r = 0; r < 4; r++)
        #pragma unroll
        for (int off = 1; off <= 8; off <<= 1)
            mx[r] = fmaxf(mx[r], __shfl_xor(mx[r], off));
    float sm[4] = {0.f, 0.f, 0.f, 0.f};
    #pragma unroll
    for (int jt = 0; jt < 24; jt++) {
        #pragma unroll
        for (int r = 0; r < 4; r++) {
            float e = __expf(acc[jt][r] - mx[r]);
            acc[jt][r] = e;
            sm[r] += e;
        }
    }
    #pragma unroll
    for (int r = 0; r < 4; r++) {
        #pragma unroll
        for (int off = 1; off <= 8; off <<= 1)
            sm[r] += __shfl_xor(sm[r], off);
        sm[r] = 1.0f / sm[r];
    }
    #pragma unroll
    for (int jt = 0; jt < 24; jt++)
        #pragma unroll
        for (int r = 0; r < 4; r++)
            P[(m0 + 4 * g + r) * 400 + jt * 16 + l15] =
                __float2bfloat16(acc[jt][r] * sm[r]);
    // each wave reads back only its own rows — no barrier

    f32x4 oacc[4];
    #pragma unroll
    for (int dn = 0; dn < 4; dn++) oacc[dn] = f32x4{0.f, 0.f, 0.f, 0.f};
    #pragma unroll
    for (int jt2 = 0; jt2 < 12; jt2++) {
        bf16x8 a = *(const bf16x8*)&P[(m0 + l15) * 400 + jt2 * 32 + 8 * g];
        #pragma unroll
        for (int dn = 0; dn < 4; dn++) {
            bf16x8 b = *(const bf16x8*)&vg[(size_t)(dn * 16 + l15) * LSEQ + jt2 * 32 + 8 * g];
            oacc[dn] = __builtin_amdgcn_mfma_f32_16x16x32_bf16(a, b, oacc[dn], 0, 0, 0);
        }
    }

    __syncthreads();   // P reads done; smem becomes O [i_loc][72]
    #pragma unroll
    for (int dn = 0; dn < 4; dn++)
        #pragma unroll
        for (int r = 0; r < 4; r++)
            O[(m0 + 4 * g + r) * 72 + dn * 16 + l15] = __float2bfloat16(oacc[dn][r]);
    __syncthreads();

    bf16* cg = ctxt + ((size_t)n * LSEQ + i0) * CHID + h * DH;
    #pragma unroll
    for (int t = 0; t < 2; t++) {
        int idx = t * 256 + tid;
        int ir = idx >> 3, u = idx & 7;
        *(uint4*)&cg[(size_t)ir * CHID + u * 8] = *(const uint4*)&O[ir * 72 + u * 8];
    }
}

// ---------------------------------------------------------------------------
extern "C" void kernel_launch(void* const* d_in, const int* in_sizes, int n_in,
                              void* d_out, int out_size, void* d_ws, size_t ws_size,
                              hipStream_t stream)
{
    const float* x       = (const float*)d_in[0];
    const float* xorg    = (const float*)d_in[1];
    const float* abspos  = (const float*)d_in[2];
    const float* mask    = (const float*)d_in[3];
    const float* norm    = (const float*)d_in[4];
    const float* qkpos   = (const float*)d_in[5];
    const float* qkorg   = (const float*)d_in[6];
    const float* vorg    = (const float*)d_in[7];
    const float* relpos  = (const float*)d_in[8];
    const float* gate_w  = (const float*)d_in[9];
    const float* gate_b  = (const float*)d_in[10];
    const float* q_w     = (const float*)d_in[11];
    const float* k_w     = (const float*)d_in[12];
    const float* v_w     = (const float*)d_in[13];
    const float* dense_w = (const float*)d_in[14];
    const float* dense_b = (const float*)d_in[15];
    float* out = (float*)d_out;

    const size_t TEN = (size_t)N_B * CHID * LSEQ * sizeof(bf16);  // 6291456 B
    const size_t WB  = (size_t)CHID * CIO * sizeof(bf16);          // 524288 B
    char* ws = (char*)d_ws;
    bf16*  x1t  = (bf16*)(ws);                 // [n][l][c]; aliased by ctxt later
    bf16*  x0t  = (bf16*)(ws + TEN);           // [n][l][c]
    bf16*  qb   = (bf16*)(ws + 2 * TEN);       // [n][h][i][d]
    bf16*  kb   = (bf16*)(ws + 3 * TEN);       // [n][h][j][d]
    bf16*  vb   = (bf16*)(ws + 4 * TEN);       // [n][c][l]
    bf16*  wqb  = (bf16*)(ws + 5 * TEN);
    bf16*  wkb  = (bf16*)(ws + 5 * TEN + WB);
    bf16*  wvb  = (bf16*)(ws + 5 * TEN + 2 * WB);
    bf16*  wdb  = (bf16*)(ws + 5 * TEN + 3 * WB);
    float* gpart = (float*)(ws + 5 * TEN + 4 * WB);  // [8][16][8][384] fp32, 1.57 MB
    bf16*  ctxt = x1t;   // x1t dead after q,k GEMMs; attn runs after them

    wconv_kernel<<<512, 256, 0, stream>>>(q_w, k_w, v_w, dense_w, wqb, wkb, wvb, wdb);
    prep_kernel<<<dim3(CIO / 64, LSEQ / 64, N_B), 256, 0, stream>>>(
        x, xorg, abspos, qkorg, qkpos, vorg, gate_w, x1t, x0t, gpart);
    mgemm_qkv_kernel<<<1152, 256, 0, stream>>>(wqb, wkb, wvb, x1t, x0t, qb, kb, vb);
    attn2_kernel<<<768, 256, 0, stream>>>(qb, kb, vb, gpart, gate_b,
                                          mask, norm, relpos, ctxt);
    mgemm_dense_kernel<<<384, 256, 0, stream>>>(wdb, ctxt, dense_b, out);
}

// Round 8
// 226.202 us; speedup vs baseline: 4.0609x; 1.0111x over previous
//
#include <hip/hip_runtime.h>
#include <hip/hip_bf16.h>

#define N_B   16
#define CIO   512
#define LSEQ  384
#define DH    64
#define NH    8
#define CHID  512
#define ME    384
#define DG    8

typedef __hip_bfloat16 bf16;
typedef __attribute__((ext_vector_type(8))) short bf16x8;
typedef __attribute__((ext_vector_type(4))) float f32x4;

__device__ __forceinline__ unsigned short f2bs(float f) {
    union { bf16 b; unsigned short u; } cv; cv.b = __float2bfloat16(f); return cv.u;
}

// ---------------------------------------------------------------------------
// wconv: cast 4 weight matrices (512x512 fp32) to bf16. 8 elems/thread.
// ---------------------------------------------------------------------------
__launch_bounds__(256)
__global__ void wconv_kernel(const float* __restrict__ w0, const float* __restrict__ w1,
                             const float* __restrict__ w2, const float* __restrict__ w3,
                             bf16* __restrict__ d0, bf16* __restrict__ d1,
                             bf16* __restrict__ d2, bf16* __restrict__ d3)
{
    int e = (blockIdx.x * 256 + threadIdx.x) * 8;
    int which = e >> 18;                  // 262144 elems per matrix
    int off = e & ((1 << 18) - 1);
    const float* s = which == 0 ? w0 : which == 1 ? w1 : which == 2 ? w2 : w3;
    bf16* d       = which == 0 ? d0 : which == 1 ? d1 : which == 2 ? d2 : d3;
    float4 f0 = *(const float4*)&s[off];
    float4 f1 = *(const float4*)&s[off + 4];
    unsigned short u[8] = {f2bs(f0.x), f2bs(f0.y), f2bs(f0.z), f2bs(f0.w),
                           f2bs(f1.x), f2bs(f1.y), f2bs(f1.z), f2bs(f1.w)};
    *(uint4*)&d[off] = *(uint4*)u;
}

// ---------------------------------------------------------------------------
// prep: X1 = x + qkorg*xorg + qkpos*abspos, X0 = x + vorg*xorg (fp32 math),
// write both bf16 TRANSPOSED [n][l][c]. 64c x 64l tile per block via LDS.
// ALSO: per-c-block partial gate into gpart[cb][n][h][l] (no atomics).
// ---------------------------------------------------------------------------
__launch_bounds__(256)
__global__ void prep_kernel(const float* __restrict__ x, const float* __restrict__ xorg,
                            const float* __restrict__ abspos,
                            const float* __restrict__ qkorg, const float* __restrict__ qkpos,
                            const float* __restrict__ vorg,
                            const float* __restrict__ gw,
                            bf16* __restrict__ x1t, bf16* __restrict__ x0t,
                            float* __restrict__ gpart)
{
    __shared__ bf16 T1[64 * 72], T0[64 * 72];   // [l][c], rows padded to 72
    __shared__ float Traw[64 * 65];             // [c][l] fp32, stride 65
    __shared__ float gws[NH * 64];              // gate_w slice [h][c_local]
    __shared__ float r0[64], r1[64], r2[64];
    const int tid = threadIdx.x;
    const int cb = blockIdx.x;
    const int c0 = cb * 64;
    const int l0 = blockIdx.y * 64;
    const int n  = blockIdx.z;
    if (tid < 64) {
        int gidx = (c0 + tid) >> 3;
        r0[tid] = vorg[gidx];
        r1[tid] = qkorg[gidx];
        r2[tid] = qkpos[gidx];
    }
    for (int t = tid; t < NH * 64; t += 256) {
        int h = t >> 6, c = t & 63;
        gws[t] = gw[h * CIO + c0 + c];
    }
    __syncthreads();
    const int l = tid & 63, cs = tid >> 6;
    #pragma unroll
    for (int r = 0; r < 16; r++) {
        int cl = r * 4 + cs;
        size_t gi = ((size_t)n * CIO + c0 + cl) * LSEQ + l0 + l;
        float xv = x[gi], xo = xorg[gi];
        Traw[cl * 65 + l] = xv;
        T0[l * 72 + cl] = __float2bfloat16(xv + r0[cl] * xo);
        T1[l * 72 + cl] = __float2bfloat16(xv + r1[cl] * xo + r2[cl] * abspos[gi]);
    }
    __syncthreads();
    for (int t = tid; t < NH * 64; t += 256) {
        int h = t >> 6, ll = t & 63;
        float s = 0.f;
        #pragma unroll
        for (int c = 0; c < 64; c++) s += gws[h * 64 + c] * Traw[c * 65 + ll];
        gpart[(((size_t)cb * N_B + n) * NH + h) * LSEQ + l0 + ll] = s;
    }
    #pragma unroll
    for (int t = 0; t < 2; t++) {
        int idx = t * 256 + tid;
        int lr = idx >> 3, u = idx & 7;
        size_t go = ((size_t)n * LSEQ + l0 + lr) * CIO + c0 + u * 8;
        *(uint4*)&x1t[go] = *(const uint4*)&T1[lr * 72 + u * 8];
        *(uint4*)&x0t[go] = *(const uint4*)&T0[lr * 72 + u * 8];
    }
}

// ---------------------------------------------------------------------------
// Merged MFMA GEMM for q/k (fused, shared B=x1t) and v. 1D grid of 768.
// XCD swizzle: residue r serves slices {qk:n=r, qk:n=r+8, v:n=r, v:n=r+8}.
// Tile 64(o) x 128(l), 4 waves; 2-stage register prefetch pipeline in K.
// ---------------------------------------------------------------------------
__launch_bounds__(256)
__global__ void mgemm_qkv_kernel(const bf16* __restrict__ wq, const bf16* __restrict__ wk,
                                 const bf16* __restrict__ wv,
                                 const bf16* __restrict__ x1t, const bf16* __restrict__ x0t,
                                 bf16* __restrict__ qb, bf16* __restrict__ kb,
                                 bf16* __restrict__ vb)
{
    __shared__ __align__(16) char smem[36864];
    const int tid = threadIdx.x;
    const int lane = tid & 63, w = tid >> 6;
    const int l15 = lane & 15, g = lane >> 4;
    const int Bid = blockIdx.x;
    const int rres = Bid & 7, qq = Bid >> 3;          // qq 0..95
    const int slice = rres + 8 * (qq / 24);           // 0..31
    const int within = qq % 24;
    const int which = slice >> 4;                     // 0 = qk fused, 1 = v
    const int n = slice & 15;
    const int l0 = (within % 3) * 128;
    const int o0 = (within / 3) * 64;

    if (which == 0) {
        // ---------------- fused q+k ----------------
        f32x4 accq[4][2], acck[4][2];
        #pragma unroll
        for (int mt = 0; mt < 4; mt++)
            #pragma unroll
            for (int jt = 0; jt < 2; jt++) {
                accq[mt][jt] = f32x4{0.f, 0.f, 0.f, 0.f};
                acck[mt][jt] = f32x4{0.f, 0.f, 0.f, 0.f};
            }
        const bf16* aqrow = wq + (size_t)(o0 + l15) * CIO + 8 * g;
        const bf16* akrow = wk + (size_t)(o0 + l15) * CIO + 8 * g;
        const bf16* brow  = x1t + ((size_t)n * LSEQ + l0 + w * 32 + l15) * CIO + 8 * g;

        bf16x8 aq[2][4], ak[2][4], bb[2][2];
        #pragma unroll
        for (int mt = 0; mt < 4; mt++) {
            aq[0][mt] = *(const bf16x8*)&aqrow[(size_t)mt * 16 * CIO];
            ak[0][mt] = *(const bf16x8*)&akrow[(size_t)mt * 16 * CIO];
        }
        #pragma unroll
        for (int jt = 0; jt < 2; jt++)
            bb[0][jt] = *(const bf16x8*)&brow[(size_t)jt * 16 * CIO];

        #pragma unroll
        for (int it = 0; it < 16; it++) {
            const int s = it & 1, ns = s ^ 1;
            if (it < 15) {
                const int kn = (it + 1) * 32;
                #pragma unroll
                for (int mt = 0; mt < 4; mt++) {
                    aq[ns][mt] = *(const bf16x8*)&aqrow[(size_t)mt * 16 * CIO + kn];
                    ak[ns][mt] = *(const bf16x8*)&akrow[(size_t)mt * 16 * CIO + kn];
                }
                #pragma unroll
                for (int jt = 0; jt < 2; jt++)
                    bb[ns][jt] = *(const bf16x8*)&brow[(size_t)jt * 16 * CIO + kn];
            }
            #pragma unroll
            for (int mt = 0; mt < 4; mt++)
                #pragma unroll
                for (int jt = 0; jt < 2; jt++) {
                    accq[mt][jt] = __builtin_amdgcn_mfma_f32_16x16x32_bf16(aq[s][mt], bb[s][jt], accq[mt][jt], 0, 0, 0);
                    acck[mt][jt] = __builtin_amdgcn_mfma_f32_16x16x32_bf16(ak[s][mt], bb[s][jt], acck[mt][jt], 0, 0, 0);
                }
        }

        // epilogue: Sq | Sk, one barrier, coalesced 16B stores
        bf16* Sq = (bf16*)smem;              // [128 l][72]
        bf16* Sk = (bf16*)(smem + 18432);
        #pragma unroll
        for (int mt = 0; mt < 4; mt++)
            #pragma unroll
            for (int jt = 0; jt < 2; jt++)
                #pragma unroll
                for (int r = 0; r < 4; r++) {
                    int row = (w * 32 + jt * 16 + l15) * 72 + mt * 16 + 4 * g + r;
                    Sq[row] = __float2bfloat16(accq[mt][jt][r]);
                    Sk[row] = __float2bfloat16(acck[mt][jt][r]);
                }
        __syncthreads();
        bf16* qg = qb + ((size_t)n * NH + (o0 >> 6)) * LSEQ * DH + (size_t)l0 * DH;
        bf16* kg = kb + ((size_t)n * NH + (o0 >> 6)) * LSEQ * DH + (size_t)l0 * DH;
        #pragma unroll
        for (int t = 0; t < 4; t++) {
            int idx = t * 256 + tid;
            int lr = idx >> 3, u = idx & 7;
            *(uint4*)&qg[(size_t)lr * DH + u * 8] = *(const uint4*)&Sq[lr * 72 + u * 8];
            *(uint4*)&kg[(size_t)lr * DH + u * 8] = *(const uint4*)&Sk[lr * 72 + u * 8];
        }
    } else {
        // ---------------- v ----------------
        f32x4 acc[4][2];
        #pragma unroll
        for (int mt = 0; mt < 4; mt++)
            #pragma unroll
            for (int jt = 0; jt < 2; jt++) acc[mt][jt] = f32x4{0.f, 0.f, 0.f, 0.f};
        const bf16* arow = wv + (size_t)(o0 + l15) * CIO + 8 * g;
        const bf16* brow = x0t + ((size_t)n * LSEQ + l0 + w * 32 + l15) * CIO + 8 * g;

        bf16x8 a[2][4], bb[2][2];
        #pragma unroll
        for (int mt = 0; mt < 4; mt++)
            a[0][mt] = *(const bf16x8*)&arow[(size_t)mt * 16 * CIO];
        #pragma unroll
        for (int jt = 0; jt < 2; jt++)
            bb[0][jt] = *(const bf16x8*)&brow[(size_t)jt * 16 * CIO];

        #pragma unroll
        for (int it = 0; it < 16; it++) {
            const int s = it & 1, ns = s ^ 1;
            if (it < 15) {
                const int kn = (it + 1) * 32;
                #pragma unroll
                for (int mt = 0; mt < 4; mt++)
                    a[ns][mt] = *(const bf16x8*)&arow[(size_t)mt * 16 * CIO + kn];
                #pragma unroll
                for (int jt = 0; jt < 2; jt++)
                    bb[ns][jt] = *(const bf16x8*)&brow[(size_t)jt * 16 * CIO + kn];
            }
            #pragma unroll
            for (int mt = 0; mt < 4; mt++)
                #pragma unroll
                for (int jt = 0; jt < 2; jt++)
                    acc[mt][jt] = __builtin_amdgcn_mfma_f32_16x16x32_bf16(a[s][mt], bb[s][jt], acc[mt][jt], 0, 0, 0);
        }

        bf16* S = (bf16*)smem;   // [64 o][136]
        #pragma unroll
        for (int mt = 0; mt < 4; mt++)
            #pragma unroll
            for (int jt = 0; jt < 2; jt++)
                #pragma unroll
                for (int r = 0; r < 4; r++)
                    S[(mt * 16 + 4 * g + r) * 136 + w * 32 + jt * 16 + l15] =
                        __float2bfloat16(acc[mt][jt][r]);
        __syncthreads();
        bf16* og = vb + ((size_t)n * CHID + o0) * LSEQ + l0;
        #pragma unroll
        for (int t = 0; t < 4; t++) {
            int idx = t * 256 + tid;
            int orow = idx >> 4, u = idx & 15;
            *(uint4*)&og[(size_t)orow * LSEQ + u * 8] = *(const uint4*)&S[orow * 136 + u * 8];
        }
    }
}

// ---------------------------------------------------------------------------
// Dense MFMA GEMM, XCD-swizzled 1D grid of 384, same 2-stage prefetch.
// ---------------------------------------------------------------------------
__launch_bounds__(256)
__global__ void mgemm_dense_kernel(const bf16* __restrict__ Wb,
                                   const bf16* __restrict__ Bt,
                                   const float* __restrict__ bias,
                                   float* __restrict__ outf)
{
    __shared__ __align__(16) float S[64 * 132];
    const int tid = threadIdx.x;
    const int lane = tid & 63, w = tid >> 6;
    const int l15 = lane & 15, g = lane >> 4;
    const int Bid = blockIdx.x;
    const int rres = Bid & 7, qq = Bid >> 3;   // qq 0..47
    const int n = rres + 8 * (qq / 24);        // 0..15
    const int within = qq % 24;
    const int l0 = (within % 3) * 128;
    const int o0 = (within / 3) * 64;

    f32x4 acc[4][2];
    #pragma unroll
    for (int mt = 0; mt < 4; mt++)
        #pragma unroll
        for (int jt = 0; jt < 2; jt++) acc[mt][jt] = f32x4{0.f, 0.f, 0.f, 0.f};

    const bf16* arow = Wb + (size_t)(o0 + l15) * CIO + 8 * g;
    const bf16* brow = Bt + ((size_t)n * LSEQ + l0 + w * 32 + l15) * CIO + 8 * g;

    bf16x8 a[2][4], bb[2][2];
    #pragma unroll
    for (int mt = 0; mt < 4; mt++)
        a[0][mt] = *(const bf16x8*)&arow[(size_t)mt * 16 * CIO];
    #pragma unroll
    for (int jt = 0; jt < 2; jt++)
        bb[0][jt] = *(const bf16x8*)&brow[(size_t)jt * 16 * CIO];

    #pragma unroll
    for (int it = 0; it < 16; it++) {
        const int s = it & 1, ns = s ^ 1;
        if (it < 15) {
            const int kn = (it + 1) * 32;
            #pragma unroll
            for (int mt = 0; mt < 4; mt++)
                a[ns][mt] = *(const bf16x8*)&arow[(size_t)mt * 16 * CIO + kn];
            #pragma unroll
            for (int jt = 0; jt < 2; jt++)
                bb[ns][jt] = *(const bf16x8*)&brow[(size_t)jt * 16 * CIO + kn];
        }
        #pragma unroll
        for (int mt = 0; mt < 4; mt++)
            #pragma unroll
            for (int jt = 0; jt < 2; jt++)
                acc[mt][jt] = __builtin_amdgcn_mfma_f32_16x16x32_bf16(a[s][mt], bb[s][jt], acc[mt][jt], 0, 0, 0);
    }

    #pragma unroll
    for (int mt = 0; mt < 4; mt++) {
        #pragma unroll
        for (int r = 0; r < 4; r++) {
            float bv = bias[o0 + mt * 16 + 4 * g + r];
            #pragma unroll
            for (int jt = 0; jt < 2; jt++)
                S[(mt * 16 + 4 * g + r) * 132 + w * 32 + jt * 16 + l15] =
                    acc[mt][jt][r] + bv;
        }
    }
    __syncthreads();
    float* og = outf + ((size_t)n * CHID + o0) * LSEQ + l0;
    #pragma unroll
    for (int t = 0; t < 8; t++) {
        int idx = t * 256 + tid;
        int orow = idx >> 5, u = idx & 31;
        *(uint4*)&og[(size_t)orow * LSEQ + u * 4] = *(const uint4*)&S[orow * 132 + u * 4];
    }
}

// ---------------------------------------------------------------------------
// MFMA attention, XCD-swizzled 1D grid of 768: residue = h.
// ---------------------------------------------------------------------------
__launch_bounds__(256)
__global__ void attn2_kernel(const bf16* __restrict__ qt,   // [n][h][i][d]
                             const bf16* __restrict__ kt,   // [n][h][j][d]
                             const bf16* __restrict__ v,    // [n][h*64+d][j]
                             const float* __restrict__ gpart,
                             const float* __restrict__ gb,
                             const float* __restrict__ mask,
                             const float* __restrict__ norm,
                             const float* __restrict__ relpos,
                             bf16* __restrict__ ctxt)
{
    __shared__ __align__(16) char smem[55296];   // Kt[384][72] | P[64][400] | O[64][72]
    __shared__ float relp_s[2 * ME - 1];
    __shared__ float radd_s[LSEQ];

    bf16* Kt = (bf16*)smem;
    bf16* P  = (bf16*)smem;
    bf16* O  = (bf16*)smem;

    const int tid = threadIdx.x;
    const int Bid = blockIdx.x;
    const int h = Bid & 7, qq = Bid >> 3;   // qq 0..95
    const int n = qq / 6;
    const int i0 = (qq % 6) * 64;
    const int lane = tid & 63;
    const int w = tid >> 6;
    const int l15 = lane & 15, g = lane >> 4;
    const int m0 = w * 16;

    const size_t nh = (size_t)n * NH + h;
    const bf16* kt_g = kt + nh * LSEQ * DH;
    const bf16* vg   = v + ((size_t)n * CHID + h * DH) * LSEQ;

    #pragma unroll
    for (int t = 0; t < 12; t++) {
        int idx = t * 256 + tid;
        int j = idx >> 3, u = idx & 7;
        *(uint4*)&Kt[j * 72 + u * 8] = *(const uint4*)&kt_g[j * 64 + u * 8];
    }
    {
        const float gbh = gb[h];
        for (int i = tid; i < LSEQ; i += 256) {
            float s = gbh + mask[(size_t)n * LSEQ + i];
            #pragma unroll
            for (int cb = 0; cb < 8; cb++)
                s += gpart[(((size_t)cb * N_B + n) * NH + h) * LSEQ + i];
            radd_s[i] = s;
        }
    }
    for (int i = tid; i < 2 * ME - 1; i += 256) relp_s[i] = relpos[i];

    const bf16* qrow = qt + (nh * LSEQ + i0 + m0 + l15) * DH;
    bf16x8 a0 = *(const bf16x8*)&qrow[8 * g];
    bf16x8 a1 = *(const bf16x8*)&qrow[8 * g + 32];
    const float inv_norm = 1.0f / norm[n];

    __syncthreads();

    f32x4 acc[24];
    #pragma unroll
    for (int jt = 0; jt < 24; jt++) acc[jt] = f32x4{0.f, 0.f, 0.f, 0.f};
    #pragma unroll
    for (int jt = 0; jt < 24; jt++) {
        const bf16* kr = &Kt[(jt * 16 + l15) * 72 + 8 * g];
        bf16x8 b0 = *(const bf16x8*)kr;
        bf16x8 b1 = *(const bf16x8*)(kr + 32);
        acc[jt] = __builtin_amdgcn_mfma_f32_16x16x32_bf16(a0, b0, acc[jt], 0, 0, 0);
        acc[jt] = __builtin_amdgcn_mfma_f32_16x16x32_bf16(a1, b1, acc[jt], 0, 0, 0);
    }

    __syncthreads();   // Kt reads done; smem becomes P

    const int ib = i0 + m0 + 4 * g;
    float mx[4] = {-1e30f, -1e30f, -1e30f, -1e30f};
    #pragma unroll
    for (int jt = 0; jt < 24; jt++) {
        float ra = radd_s[jt * 16 + l15];
        #pragma unroll
        for (int r = 0; r < 4; r++) {
            int idx = ME - (ib + r) + jt * 16 + l15;
            idx = (idx > 2 * ME - 2) ? (2 * ME - 2) : idx;
            float s = (acc[jt][r] + relp_s[idx] + ra) * inv_norm;
            acc[jt][r] = s;
            mx[r] = fmaxf(mx[r], s);
        }
    }
    #pragma unroll
    for (int r = 0; r < 4; r++)
        #pragma unroll
        for (int off = 1; off <= 8; off <<= 1)
            mx[r] = fmaxf(mx[r], __shfl_xor(mx[r], off));
    float sm[4] = {0.f, 0.f, 0.f, 0.f};
    #pragma unroll
    for (int jt = 0; jt < 24; jt++) {
        #pragma unroll
        for (int r = 0; r < 4; r++) {
            float e = __expf(acc[jt][r] - mx[r]);
            acc[jt][r] = e;
            sm[r] += e;
        }
    }
    #pragma unroll
    for (int r = 0; r < 4; r++) {
        #pragma unroll
        for (int off = 1; off <= 8; off <<= 1)
            sm[r] += __shfl_xor(sm[r], off);
        sm[r] = 1.0f / sm[r];
    }
    #pragma unroll
    for (int jt = 0; jt < 24; jt++)
        #pragma unroll
        for (int r = 0; r < 4; r++)
            P[(m0 + 4 * g + r) * 400 + jt * 16 + l15] =
                __float2bfloat16(acc[jt][r] * sm[r]);
    // each wave reads back only its own rows — no barrier

    f32x4 oacc[4];
    #pragma unroll
    for (int dn = 0; dn < 4; dn++) oacc[dn] = f32x4{0.f, 0.f, 0.f, 0.f};
    #pragma unroll
    for (int jt2 = 0; jt2 < 12; jt2++) {
        bf16x8 a = *(const bf16x8*)&P[(m0 + l15) * 400 + jt2 * 32 + 8 * g];
        #pragma unroll
        for (int dn = 0; dn < 4; dn++) {
            bf16x8 b = *(const bf16x8*)&vg[(size_t)(dn * 16 + l15) * LSEQ + jt2 * 32 + 8 * g];
            oacc[dn] = __builtin_amdgcn_mfma_f32_16x16x32_bf16(a, b, oacc[dn], 0, 0, 0);
        }
    }

    __syncthreads();   // P reads done; smem becomes O [i_loc][72]
    #pragma unroll
    for (int dn = 0; dn < 4; dn++)
        #pragma unroll
        for (int r = 0; r < 4; r++)
            O[(m0 + 4 * g + r) * 72 + dn * 16 + l15] = __float2bfloat16(oacc[dn][r]);
    __syncthreads();

    bf16* cg = ctxt + ((size_t)n * LSEQ + i0) * CHID + h * DH;
    #pragma unroll
    for (int t = 0; t < 2; t++) {
        int idx = t * 256 + tid;
        int ir = idx >> 3, u = idx & 7;
        *(uint4*)&cg[(size_t)ir * CHID + u * 8] = *(const uint4*)&O[ir * 72 + u * 8];
    }
}

// ---------------------------------------------------------------------------
extern "C" void kernel_launch(void* const* d_in, const int* in_sizes, int n_in,
                              void* d_out, int out_size, void* d_ws, size_t ws_size,
                              hipStream_t stream)
{
    const float* x       = (const float*)d_in[0];
    const float* xorg    = (const float*)d_in[1];
    const float* abspos  = (const float*)d_in[2];
    const float* mask    = (const float*)d_in[3];
    const float* norm    = (const float*)d_in[4];
    const float* qkpos   = (const float*)d_in[5];
    const float* qkorg   = (const float*)d_in[6];
    const float* vorg    = (const float*)d_in[7];
    const float* relpos  = (const float*)d_in[8];
    const float* gate_w  = (const float*)d_in[9];
    const float* gate_b  = (const float*)d_in[10];
    const float* q_w     = (const float*)d_in[11];
    const float* k_w     = (const float*)d_in[12];
    const float* v_w     = (const float*)d_in[13];
    const float* dense_w = (const float*)d_in[14];
    const float* dense_b = (const float*)d_in[15];
    float* out = (float*)d_out;

    const size_t TEN = (size_t)N_B * CHID * LSEQ * sizeof(bf16);  // 6291456 B
    const size_t WB  = (size_t)CHID * CIO * sizeof(bf16);          // 524288 B
    char* ws = (char*)d_ws;
    bf16*  x1t  = (bf16*)(ws);                 // [n][l][c]; aliased by ctxt later
    bf16*  x0t  = (bf16*)(ws + TEN);           // [n][l][c]
    bf16*  qb   = (bf16*)(ws + 2 * TEN);       // [n][h][i][d]
    bf16*  kb   = (bf16*)(ws + 3 * TEN);       // [n][h][j][d]
    bf16*  vb   = (bf16*)(ws + 4 * TEN);       // [n][c][l]
    bf16*  wqb  = (bf16*)(ws + 5 * TEN);
    bf16*  wkb  = (bf16*)(ws + 5 * TEN + WB);
    bf16*  wvb  = (bf16*)(ws + 5 * TEN + 2 * WB);
    bf16*  wdb  = (bf16*)(ws + 5 * TEN + 3 * WB);
    float* gpart = (float*)(ws + 5 * TEN + 4 * WB);  // [8][16][8][384] fp32, 1.57 MB
    bf16*  ctxt = x1t;   // x1t dead after q,k GEMMs; attn runs after them

    wconv_kernel<<<512, 256, 0, stream>>>(q_w, k_w, v_w, dense_w, wqb, wkb, wvb, wdb);
    prep_kernel<<<dim3(CIO / 64, LSEQ / 64, N_B), 256, 0, stream>>>(
        x, xorg, abspos, qkorg, qkpos, vorg, gate_w, x1t, x0t, gpart);
    mgemm_qkv_kernel<<<768, 256, 0, stream>>>(wqb, wkb, wvb, x1t, x0t, qb, kb, vb);
    attn2_kernel<<<768, 256, 0, stream>>>(qb, kb, vb, gpart, gate_b,
                                          mask, norm, relpos, ctxt);
    mgemm_dense_kernel<<<384, 256, 0, stream>>>(wdb, ctxt, dense_b, out);
}